// Round 1
// baseline (576.262 us; speedup 1.0000x reference)
//
#include <hip/hip_runtime.h>
#include <math.h>

typedef __bf16 bf16x8 __attribute__((ext_vector_type(8)));
typedef float  f32x4  __attribute__((ext_vector_type(4)));
typedef unsigned short u16x4 __attribute__((ext_vector_type(4)));

#define DEVI __device__ __forceinline__

static constexpr int NB  = 8;
static constexpr int NN  = 2048;
static constexpr int NF  = 128;
static constexpr int NC2 = 256;                    // [W_emb | W_pool] width

static constexpr int OUT_X0  = 0;                  // X_pooled [8,128,128]
static constexpr int OUT_A0  = NB * 128 * 128;     // A_pooled [8,128,128]
static constexpr int OUT_S0  = OUT_A0 + NB * 128 * 128;   // S [8,2048,128]
static constexpr int OUT_LP  = OUT_S0 + NB * NN * 128;    // LP_loss scalar
static constexpr int OUT_ENT = OUT_LP + 1;                // entr_loss scalar

DEVI unsigned short f2b(float f) {                 // fp32 -> bf16 (RNE)
  unsigned int u = __builtin_bit_cast(unsigned int, f);
  u += 0x7fffu + ((u >> 16) & 1u);
  return (unsigned short)(u >> 16);
}
DEVI float b2f(unsigned short h) {
  unsigned int u = ((unsigned int)h) << 16;
  return __builtin_bit_cast(float, u);
}
DEVI void load_lds16(const void* g, void* l) {
  __builtin_amdgcn_global_load_lds(
      (const __attribute__((address_space(1))) void*)g,
      (__attribute__((address_space(3))) void*)l, 16, 0, 0);
}

// ---- 128x128x(K) bf16 MFMA GEMM core (B operand stored transposed [col][k]) ----
// LDS tile: 128 rows x 32 k, slot s = row*4 + c (16B each); slot holds global
// k-chunk (c ^ (row&3)): staging stays 64B-line coalesced, frag reads bank-spread.
DEVI void stage_tile(const unsigned short* src, int ld, unsigned short* dst,
                     int k0, int tid) {
  const int wave = tid >> 6;
#pragma unroll
  for (int is = 0; is < 2; ++is) {
    const int row = is * 64 + (tid >> 2);
    const int c   = tid & 3;
    const unsigned short* g = src + row * ld + k0 + ((c ^ (row & 3)) << 3);
    unsigned short* l = dst + ((is * 256 + wave * 64) << 3);  // wave-uniform base
    load_lds16(g, l);
  }
}

DEVI void gemm_core(const unsigned short* Aop, int lda,
                    const unsigned short* Bop, int ldb, int ksteps,
                    unsigned short* lA0, unsigned short* lA1,
                    unsigned short* lB0, unsigned short* lB1,
                    int tid, f32x4 (&acc)[4][4]) {
  const int lane = tid & 63;
  const int wave = tid >> 6;
  const int wr = wave >> 1, wc = wave & 1;
  const int l15 = lane & 15;
  const int sx = (lane >> 4) ^ (l15 & 3);
#pragma unroll
  for (int i = 0; i < 4; ++i) {
#pragma unroll
    for (int j = 0; j < 4; ++j) acc[i][j] = (f32x4){0.f, 0.f, 0.f, 0.f};
  }
  stage_tile(Aop, lda, lA0, 0, tid);
  stage_tile(Bop, ldb, lB0, 0, tid);
  __syncthreads();
  for (int kt = 0; kt < ksteps; ++kt) {
    unsigned short* curA = (kt & 1) ? lA1 : lA0;
    unsigned short* curB = (kt & 1) ? lB1 : lB0;
    if (kt + 1 < ksteps) {
      unsigned short* nxtA = (kt & 1) ? lA0 : lA1;
      unsigned short* nxtB = (kt & 1) ? lB0 : lB1;
      stage_tile(Aop, lda, nxtA, (kt + 1) * 32, tid);
      stage_tile(Bop, ldb, nxtB, (kt + 1) * 32, tid);
    }
    bf16x8 af[4], bg[4];
#pragma unroll
    for (int i = 0; i < 4; ++i) {
      const int row = wr * 64 + i * 16 + l15;
      af[i] = *(const bf16x8*)(curA + ((row * 4 + sx) << 3));
    }
#pragma unroll
    for (int j = 0; j < 4; ++j) {
      const int col = wc * 64 + j * 16 + l15;
      bg[j] = *(const bf16x8*)(curB + ((col * 4 + sx) << 3));
    }
#pragma unroll
    for (int i = 0; i < 4; ++i) {
#pragma unroll
      for (int j = 0; j < 4; ++j)
        acc[i][j] = __builtin_amdgcn_mfma_f32_16x16x32_bf16(af[i], bg[j],
                                                            acc[i][j], 0, 0, 0);
    }
    __syncthreads();
  }
}

// ---- small kernels ----
__global__ __launch_bounds__(64) void k_zero(float* accv) {
  if (threadIdx.x < 16) accv[threadIdx.x] = 0.f;
}

// A fp32 -> bf16, rowsum -> d = rsqrt(rowsum+1), nnz[b] += rowsum
__global__ __launch_bounds__(256) void k_prep_a(const float* __restrict__ A,
                                                unsigned short* __restrict__ AB,
                                                float* __restrict__ dvec,
                                                float* accv) {
  const int row = blockIdx.x * 4 + (threadIdx.x >> 6);
  const int lane = threadIdx.x & 63;
  const f32x4* src = (const f32x4*)(A + ((size_t)row << 11));
  u16x4* dst = (u16x4*)(AB + ((size_t)row << 11));
  float s = 0.f;
#pragma unroll
  for (int it = 0; it < 8; ++it) {
    f32x4 v = src[it * 64 + lane];
    s += v[0] + v[1] + v[2] + v[3];
    u16x4 o;
    o[0] = f2b(v[0]); o[1] = f2b(v[1]); o[2] = f2b(v[2]); o[3] = f2b(v[3]);
    dst[it * 64 + lane] = o;
  }
#pragma unroll
  for (int o2 = 32; o2; o2 >>= 1) s += __shfl_down(s, o2);
  if (lane == 0) {
    dvec[row] = rsqrtf(s + 1.f);
    atomicAdd(&accv[row >> 11], s);   // nnz per graph (exact: integer sums)
  }
}

__global__ __launch_bounds__(256) void k_conv_x(const float* __restrict__ X,
                                                unsigned short* __restrict__ XB) {
  const int i0 = blockIdx.x * 1024 + threadIdx.x;
  const f32x4* src = (const f32x4*)X;
  u16x4* dst = (u16x4*)XB;
#pragma unroll
  for (int it = 0; it < 4; ++it) {
    const int idx = i0 + it * 256;
    f32x4 v = src[idx];
    u16x4 o;
    o[0] = f2b(v[0]); o[1] = f2b(v[1]); o[2] = f2b(v[2]); o[3] = f2b(v[3]);
    dst[idx] = o;
  }
}

// WT[c][f] = W[f][c] for c<128 from W_emb else W_pool (bf16)
__global__ __launch_bounds__(128) void k_prep_w(const float* __restrict__ Wemb,
                                                const float* __restrict__ Wpool,
                                                unsigned short* __restrict__ WT) {
  const int c = blockIdx.x, f = threadIdx.x;
  const float v = (c < 128) ? Wemb[f * 128 + c] : Wpool[f * 128 + (c - 128)];
  WT[c * 128 + f] = f2b(v);
}

// V_T[b][c][n] = bf16( d[b,n] * (X @ Wcat)[b,n,c] )   (transposed store)
__global__ __launch_bounds__(256) void k_gemm_xw(const unsigned short* __restrict__ XB,
                                                 const unsigned short* __restrict__ WT,
                                                 const float* __restrict__ dvec,
                                                 unsigned short* __restrict__ VT) {
  __shared__ unsigned short lA[2][4096], lB[2][4096];
  const int mt = blockIdx.x, ct = blockIdx.y, tid = threadIdx.x;
  f32x4 acc[4][4];
  gemm_core(XB + mt * 128 * NF, NF, WT + ct * 128 * NF, NF, NF / 32,
            lA[0], lA[1], lB[0], lB[1], tid, acc);
  const int lane = tid & 63, wave = tid >> 6;
  const int wr = wave >> 1, wc = wave & 1, l15 = lane & 15, l4 = (lane >> 4) * 4;
#pragma unroll
  for (int i = 0; i < 4; ++i) {
    const int gr0 = mt * 128 + wr * 64 + i * 16 + l4;   // global row (b*2048+n)
    const int b = gr0 >> 11, n0 = gr0 & 2047;
#pragma unroll
    for (int j = 0; j < 4; ++j) {
      const int gc = ct * 128 + wc * 64 + j * 16 + l15;
      u16x4 pk;
#pragma unroll
      for (int r = 0; r < 4; ++r) pk[r] = f2b(acc[i][j][r] * dvec[gr0 + r]);
      *(u16x4*)(VT + (((size_t)(b * NC2 + gc)) << 11) + n0) = pk;
    }
  }
}

// U = A@V + V, row-scaled by d.  ct==0 -> Z_T bf16 (YT rows 0..127)
//                               ct==1 -> S_pre_T fp32 (softmax input)
__global__ __launch_bounds__(256) void k_gemm_nv(const unsigned short* __restrict__ AB,
                                                 const unsigned short* __restrict__ VT,
                                                 const float* __restrict__ dvec,
                                                 unsigned short* YT, float* SpT) {
  __shared__ unsigned short lA[2][4096], lB[2][4096];
  const int mt = blockIdx.x, ct = blockIdx.y, b = blockIdx.z, tid = threadIdx.x;
  const unsigned short* Aop = AB + ((size_t)b << 22) + (size_t)mt * 128 * NN;
  const unsigned short* Bop = VT + (((size_t)(b * NC2 + ct * 128)) << 11);
  f32x4 acc[4][4];
  gemm_core(Aop, NN, Bop, NN, NN / 32, lA[0], lA[1], lB[0], lB[1], tid, acc);
  const int lane = tid & 63, wave = tid >> 6;
  const int wr = wave >> 1, wc = wave & 1, l15 = lane & 15, l4 = (lane >> 4) * 4;
#pragma unroll
  for (int i = 0; i < 4; ++i) {
    const int n0 = mt * 128 + wr * 64 + i * 16 + l4;
#pragma unroll
    for (int j = 0; j < 4; ++j) {
      const int c = ct * 128 + wc * 64 + j * 16 + l15;   // 0..255
      const unsigned short* vt = VT + (((size_t)(b * NC2 + c)) << 11);
      if (ct == 0) {
        u16x4 pk;
#pragma unroll
        for (int r = 0; r < 4; ++r)
          pk[r] = f2b((acc[i][j][r] + b2f(vt[n0 + r])) * dvec[(b << 11) + n0 + r]);
        *(u16x4*)(YT + (((size_t)(b * 384 + c)) << 11) + n0) = pk;
      } else {
        f32x4 pk;
#pragma unroll
        for (int r = 0; r < 4; ++r)
          pk[r] = (acc[i][j][r] + b2f(vt[n0 + r])) * dvec[(b << 11) + n0 + r];
        *(f32x4*)(SpT + (((size_t)(b * 128 + (c - 128))) << 11) + n0) = pk;
      }
    }
  }
}

// row softmax over k=128; writes S fp32 (d_out) + S_T bf16 (YT rows 256..383);
// entropy via  entr = log s - <p, x-m>  (eps shift negligible: ~1e-5)
__global__ __launch_bounds__(128) void k_softmax(const float* __restrict__ SpT,
                                                 float* __restrict__ out,
                                                 unsigned short* __restrict__ YT,
                                                 float* accv) {
  const int t = blockIdx.x, b = blockIdx.y;       // 32 x 8
  const int tid = threadIdx.x;
  const int h = tid >> 6, r = tid & 63;
  const int n = t * 64 + r;
  const float* src = SpT + (((size_t)(b * 128 + h * 64)) << 11) + n;
  float x[64];
  float m = -1e30f;
#pragma unroll
  for (int k = 0; k < 64; ++k) { x[k] = src[(size_t)k << 11]; m = fmaxf(m, x[k]); }
  __shared__ float smx[2][64], sms[2][64], smt[2][64];
  smx[h][r] = m;
  __syncthreads();
  m = fmaxf(smx[0][r], smx[1][r]);
  float s = 0.f, tt = 0.f;
#pragma unroll
  for (int k = 0; k < 64; ++k) {
    const float e = __expf(x[k] - m);
    s += e; tt += (x[k] - m) * e; x[k] = e;
  }
  sms[h][r] = s; smt[h][r] = tt;
  __syncthreads();
  s = sms[0][r] + sms[1][r];
  tt = smt[0][r] + smt[1][r];
  const float inv = 1.f / s;
  float* po = out + OUT_S0 + (((size_t)(b * NN + n)) << 7) + h * 64;
#pragma unroll
  for (int k4 = 0; k4 < 16; ++k4) {
    f32x4 v;
    v[0] = x[k4*4+0]*inv; v[1] = x[k4*4+1]*inv; v[2] = x[k4*4+2]*inv; v[3] = x[k4*4+3]*inv;
    *(f32x4*)(po + k4 * 4) = v;
  }
  unsigned short* pt = YT + (((size_t)(b * 384 + 256 + h * 64)) << 11) + n;
#pragma unroll
  for (int k = 0; k < 64; ++k) pt[(size_t)k << 11] = f2b(x[k] * inv);
  if (h == 0) {
    float entr = __logf(s) - tt * inv;
#pragma unroll
    for (int o2 = 32; o2; o2 >>= 1) entr += __shfl_down(entr, o2);
    if (tid == 0) atomicAdd(&accv[8], entr);
  }
}

// AS_T = (A @ S)^T  -> YT rows 128..255
__global__ __launch_bounds__(256) void k_gemm_as(const unsigned short* __restrict__ AB,
                                                 unsigned short* YT) {
  __shared__ unsigned short lA[2][4096], lB[2][4096];
  const int mt = blockIdx.x, b = blockIdx.z, tid = threadIdx.x;
  const unsigned short* Aop = AB + ((size_t)b << 22) + (size_t)mt * 128 * NN;
  const unsigned short* Bop = YT + (((size_t)(b * 384 + 256)) << 11);
  f32x4 acc[4][4];
  gemm_core(Aop, NN, Bop, NN, NN / 32, lA[0], lA[1], lB[0], lB[1], tid, acc);
  const int lane = tid & 63, wave = tid >> 6;
  const int wr = wave >> 1, wc = wave & 1, l15 = lane & 15, l4 = (lane >> 4) * 4;
#pragma unroll
  for (int i = 0; i < 4; ++i) {
    const int n0 = mt * 128 + wr * 64 + i * 16 + l4;
#pragma unroll
    for (int j = 0; j < 4; ++j) {
      const int c = wc * 64 + j * 16 + l15;
      u16x4 pk;
#pragma unroll
      for (int r = 0; r < 4; ++r) pk[r] = f2b(acc[i][j][r]);
      *(u16x4*)(YT + (((size_t)(b * 384 + 128 + c)) << 11) + n0) = pk;
    }
  }
}

// P = S^T @ [Z | AS | S]  (M=128, N=384, K=2048, split-K=8) -> fp32 partials
__global__ __launch_bounds__(256) void k_gemm_p(const unsigned short* __restrict__ YT,
                                                float* __restrict__ Pp) {
  __shared__ unsigned short lA[2][4096], lB[2][4096];
  const int ct = blockIdx.x, sk = blockIdx.y, b = blockIdx.z, tid = threadIdx.x;
  const unsigned short* Aop = YT + (((size_t)(b * 384 + 256)) << 11) + sk * 256;
  const unsigned short* Bop = YT + (((size_t)(b * 384 + ct * 128)) << 11) + sk * 256;
  f32x4 acc[4][4];
  gemm_core(Aop, NN, Bop, NN, 8, lA[0], lA[1], lB[0], lB[1], tid, acc);
  const int lane = tid & 63, wave = tid >> 6;
  const int wr = wave >> 1, wc = wave & 1, l15 = lane & 15, l4 = (lane >> 4) * 4;
  float* dst = Pp + ((size_t)(sk * NB + b)) * 128 * 384;
#pragma unroll
  for (int i = 0; i < 4; ++i) {
    const int p0 = wr * 64 + i * 16 + l4;
#pragma unroll
    for (int j = 0; j < 4; ++j) {
      const int gc = ct * 128 + wc * 64 + j * 16 + l15;
#pragma unroll
      for (int r = 0; r < 4; ++r) dst[(p0 + r) * 384 + gc] = acc[i][j][r];
    }
  }
}

// sum split-K partials; write X_pooled / A_pooled; per-batch trace + ||S^T S||^2
// -> LP_b = sqrt(nnz_b - 2 tr + g2);  accv[9] += LP_b/8
__global__ __launch_bounds__(256) void k_finalize(const float* __restrict__ Pp,
                                                  float* accv, float* __restrict__ out) {
  const int b = blockIdx.x, tid = threadIdx.x;
  float tr = 0.f, g2 = 0.f;
  for (int e = tid; e < 128 * 384; e += 256) {
    const int p = e / 384, c = e % 384;
    float s = 0.f;
#pragma unroll
    for (int sk = 0; sk < 8; ++sk)
      s += Pp[(((size_t)(sk * NB + b)) * 128 + p) * 384 + c];
    if (c < 128) {
      out[OUT_X0 + ((size_t)(b * 128 + p)) * 128 + c] = s;
    } else if (c < 256) {
      out[OUT_A0 + ((size_t)(b * 128 + p)) * 128 + (c - 128)] = s;
      if (c - 128 == p) tr += s;
    } else {
      g2 += s * s;
    }
  }
  __shared__ float rbuf[512];
  rbuf[tid] = tr; rbuf[256 + tid] = g2;
  __syncthreads();
  for (int o = 128; o; o >>= 1) {
    if (tid < o) { rbuf[tid] += rbuf[tid + o]; rbuf[256 + tid] += rbuf[256 + tid + o]; }
    __syncthreads();
  }
  if (tid == 0) {
    const float lp2 = accv[b] - 2.f * rbuf[0] + rbuf[256];
    atomicAdd(&accv[9], 0.125f * sqrtf(fmaxf(lp2, 0.f)));
  }
}

__global__ __launch_bounds__(64) void k_losses(const float* accv, float* out) {
  if (threadIdx.x == 0) {
    out[OUT_LP] = accv[9];
    out[OUT_ENT] = accv[8] * (1.f / (NB * NN));
  }
}

extern "C" void kernel_launch(void* const* d_in, const int* in_sizes, int n_in,
                              void* d_out, int out_size, void* d_ws, size_t ws_size,
                              hipStream_t stream) {
  const float* X     = (const float*)d_in[0];
  const float* A     = (const float*)d_in[1];
  const float* Wemb  = (const float*)d_in[2];
  const float* Wpool = (const float*)d_in[3];
  float* out = (float*)d_out;

  char* ws = (char*)d_ws;
  size_t o = 0;
  unsigned short* AB = (unsigned short*)(ws + o); o += (size_t)NB * NN * NN * 2;   // 64 MiB
  unsigned short* XB = (unsigned short*)(ws + o); o += (size_t)NB * NN * NF * 2;
  unsigned short* WT = (unsigned short*)(ws + o); o += (size_t)NC2 * NF * 2;
  unsigned short* VT = (unsigned short*)(ws + o); o += (size_t)NB * NC2 * NN * 2;
  unsigned short* YT = (unsigned short*)(ws + o); o += (size_t)NB * 384 * NN * 2;  // [Z|AS|S]^T
  float* SpT = (float*)(ws + o); o += (size_t)NB * 128 * NN * 4;
  float* Pp  = (float*)(ws + o); o += (size_t)8 * NB * 128 * 384 * 4;
  float* dvec = (float*)(ws + o); o += (size_t)NB * NN * 4;
  float* accv = (float*)(ws + o); o += 256;   // [0..7]=nnz_b, [8]=entropy, [9]=LP

  k_zero    <<<1, 64, 0, stream>>>(accv);
  k_prep_a  <<<dim3(NB * NN / 4), 256, 0, stream>>>(A, AB, dvec, accv);
  k_conv_x  <<<dim3(512), 256, 0, stream>>>(X, XB);
  k_prep_w  <<<dim3(NC2), 128, 0, stream>>>(Wemb, Wpool, WT);
  k_gemm_xw <<<dim3(NB * NN / 128, 2), 256, 0, stream>>>(XB, WT, dvec, VT);
  k_gemm_nv <<<dim3(NN / 128, 2, NB), 256, 0, stream>>>(AB, VT, dvec, YT, SpT);
  k_softmax <<<dim3(NN / 64, NB), 128, 0, stream>>>(SpT, out, YT, accv);
  k_gemm_as <<<dim3(NN / 128, 1, NB), 256, 0, stream>>>(AB, YT);
  k_gemm_p  <<<dim3(3, 8, NB), 256, 0, stream>>>(YT, Pp);
  k_finalize<<<dim3(NB), 256, 0, stream>>>(Pp, accv, out);
  k_losses  <<<1, 64, 0, stream>>>(accv, out);
}

// Round 2
// 419.670 us; speedup vs baseline: 1.3731x; 1.3731x over previous
//
#include <hip/hip_runtime.h>
#include <math.h>

typedef __bf16 bf16x8 __attribute__((ext_vector_type(8)));
typedef float  f32x4  __attribute__((ext_vector_type(4)));
typedef unsigned short u16x4 __attribute__((ext_vector_type(4)));

#define DEVI __device__ __forceinline__

static constexpr int NB  = 8;
static constexpr int NN  = 2048;
static constexpr int NF  = 128;
static constexpr int NC2 = 256;                    // [W_emb | W_pool] width

static constexpr int OUT_X0  = 0;                  // X_pooled [8,128,128]
static constexpr int OUT_A0  = NB * 128 * 128;     // A_pooled [8,128,128]
static constexpr int OUT_S0  = OUT_A0 + NB * 128 * 128;   // S [8,2048,128]
static constexpr int OUT_LP  = OUT_S0 + NB * NN * 128;    // LP_loss scalar
static constexpr int OUT_ENT = OUT_LP + 1;                // entr_loss scalar

DEVI unsigned short f2b(float f) {                 // fp32 -> bf16 (RNE)
  unsigned int u = __builtin_bit_cast(unsigned int, f);
  u += 0x7fffu + ((u >> 16) & 1u);
  return (unsigned short)(u >> 16);
}
DEVI float b2f(unsigned short h) {
  unsigned int u = ((unsigned int)h) << 16;
  return __builtin_bit_cast(float, u);
}
DEVI void load_lds16(const void* g, void* l) {
  __builtin_amdgcn_global_load_lds(
      (const __attribute__((address_space(1))) void*)g,
      (__attribute__((address_space(3))) void*)l, 16, 0, 0);
}

// ---- 128x128x(K) bf16 MFMA GEMM core (B operand stored transposed [col][k]) ----
// LDS tile: 128 rows x 32 k, slot s = row*4 + c (16B each); slot holds global
// k-chunk (c ^ (row&3)): staging stays 64B-line coalesced, frag reads bank-spread.
DEVI void stage_tile(const unsigned short* src, int ld, unsigned short* dst,
                     int k0, int tid) {
  const int wave = tid >> 6;
#pragma unroll
  for (int is = 0; is < 2; ++is) {
    const int row = is * 64 + (tid >> 2);
    const int c   = tid & 3;
    const unsigned short* g = src + row * ld + k0 + ((c ^ (row & 3)) << 3);
    unsigned short* l = dst + ((is * 256 + wave * 64) << 3);  // wave-uniform base
    load_lds16(g, l);
  }
}

DEVI void gemm_core(const unsigned short* Aop, int lda,
                    const unsigned short* Bop, int ldb, int ksteps,
                    unsigned short* lA0, unsigned short* lA1,
                    unsigned short* lB0, unsigned short* lB1,
                    int tid, f32x4 (&acc)[4][4]) {
  const int lane = tid & 63;
  const int wave = tid >> 6;
  const int wr = wave >> 1, wc = wave & 1;
  const int l15 = lane & 15;
  const int sx = (lane >> 4) ^ (l15 & 3);
#pragma unroll
  for (int i = 0; i < 4; ++i) {
#pragma unroll
    for (int j = 0; j < 4; ++j) acc[i][j] = (f32x4){0.f, 0.f, 0.f, 0.f};
  }
  stage_tile(Aop, lda, lA0, 0, tid);
  stage_tile(Bop, ldb, lB0, 0, tid);
  __syncthreads();
  for (int kt = 0; kt < ksteps; ++kt) {
    unsigned short* curA = (kt & 1) ? lA1 : lA0;
    unsigned short* curB = (kt & 1) ? lB1 : lB0;
    if (kt + 1 < ksteps) {
      unsigned short* nxtA = (kt & 1) ? lA0 : lA1;
      unsigned short* nxtB = (kt & 1) ? lB0 : lB1;
      stage_tile(Aop, lda, nxtA, (kt + 1) * 32, tid);
      stage_tile(Bop, ldb, nxtB, (kt + 1) * 32, tid);
    }
    bf16x8 af[4], bg[4];
#pragma unroll
    for (int i = 0; i < 4; ++i) {
      const int row = wr * 64 + i * 16 + l15;
      af[i] = *(const bf16x8*)(curA + ((row * 4 + sx) << 3));
    }
#pragma unroll
    for (int j = 0; j < 4; ++j) {
      const int col = wc * 64 + j * 16 + l15;
      bg[j] = *(const bf16x8*)(curB + ((col * 4 + sx) << 3));
    }
#pragma unroll
    for (int i = 0; i < 4; ++i) {
#pragma unroll
      for (int j = 0; j < 4; ++j)
        acc[i][j] = __builtin_amdgcn_mfma_f32_16x16x32_bf16(af[i], bg[j],
                                                            acc[i][j], 0, 0, 0);
    }
    __syncthreads();
  }
}

// ---- small kernels ----
__global__ __launch_bounds__(64) void k_zero(float* accv) {
  if (threadIdx.x < 16) accv[threadIdx.x] = 0.f;
}

// A fp32 -> bf16, rowsum -> d = rsqrt(rowsum+1); rsum[row] = rowsum (NO atomics)
__global__ __launch_bounds__(256) void k_prep_a(const float* __restrict__ A,
                                                unsigned short* __restrict__ AB,
                                                float* __restrict__ dvec,
                                                float* __restrict__ rsum) {
  const int row = blockIdx.x * 4 + (threadIdx.x >> 6);
  const int lane = threadIdx.x & 63;
  const f32x4* src = (const f32x4*)(A + ((size_t)row << 11));
  u16x4* dst = (u16x4*)(AB + ((size_t)row << 11));
  float s = 0.f;
#pragma unroll
  for (int it = 0; it < 8; ++it) {
    f32x4 v = src[it * 64 + lane];
    s += v[0] + v[1] + v[2] + v[3];
    u16x4 o;
    o[0] = f2b(v[0]); o[1] = f2b(v[1]); o[2] = f2b(v[2]); o[3] = f2b(v[3]);
    dst[it * 64 + lane] = o;
  }
#pragma unroll
  for (int o2 = 32; o2; o2 >>= 1) s += __shfl_down(s, o2);
  if (lane == 0) {
    dvec[row] = rsqrtf(s + 1.f);
    rsum[row] = s;
  }
}

__global__ __launch_bounds__(256) void k_conv_x(const float* __restrict__ X,
                                                unsigned short* __restrict__ XB) {
  const int i0 = blockIdx.x * 1024 + threadIdx.x;
  const f32x4* src = (const f32x4*)X;
  u16x4* dst = (u16x4*)XB;
#pragma unroll
  for (int it = 0; it < 4; ++it) {
    const int idx = i0 + it * 256;
    f32x4 v = src[idx];
    u16x4 o;
    o[0] = f2b(v[0]); o[1] = f2b(v[1]); o[2] = f2b(v[2]); o[3] = f2b(v[3]);
    dst[idx] = o;
  }
}

// WT[c][f] = W[f][c] for c<128 from W_emb else W_pool (bf16)
__global__ __launch_bounds__(128) void k_prep_w(const float* __restrict__ Wemb,
                                                const float* __restrict__ Wpool,
                                                unsigned short* __restrict__ WT) {
  const int c = blockIdx.x, f = threadIdx.x;
  const float v = (c < 128) ? Wemb[f * 128 + c] : Wpool[f * 128 + (c - 128)];
  WT[c * 128 + f] = f2b(v);
}

// V_T[b][c][n] = bf16( d[b,n] * (X @ Wcat)[b,n,c] )   (transposed store)
__global__ __launch_bounds__(256) void k_gemm_xw(const unsigned short* __restrict__ XB,
                                                 const unsigned short* __restrict__ WT,
                                                 const float* __restrict__ dvec,
                                                 unsigned short* __restrict__ VT) {
  __shared__ unsigned short lA[2][4096], lB[2][4096];
  const int mt = blockIdx.x, ct = blockIdx.y, tid = threadIdx.x;
  f32x4 acc[4][4];
  gemm_core(XB + mt * 128 * NF, NF, WT + ct * 128 * NF, NF, NF / 32,
            lA[0], lA[1], lB[0], lB[1], tid, acc);
  const int lane = tid & 63, wave = tid >> 6;
  const int wr = wave >> 1, wc = wave & 1, l15 = lane & 15, l4 = (lane >> 4) * 4;
#pragma unroll
  for (int i = 0; i < 4; ++i) {
    const int gr0 = mt * 128 + wr * 64 + i * 16 + l4;   // global row (b*2048+n)
    const int b = gr0 >> 11, n0 = gr0 & 2047;
#pragma unroll
    for (int j = 0; j < 4; ++j) {
      const int gc = ct * 128 + wc * 64 + j * 16 + l15;
      u16x4 pk;
#pragma unroll
      for (int r = 0; r < 4; ++r) pk[r] = f2b(acc[i][j][r] * dvec[gr0 + r]);
      *(u16x4*)(VT + (((size_t)(b * NC2 + gc)) << 11) + n0) = pk;
    }
  }
}

// U = A@V + V, row-scaled by d.  ct==0 -> Z_T bf16 (YT rows 0..127)
//                               ct==1 -> S_pre_T fp32 (softmax input)
__global__ __launch_bounds__(256) void k_gemm_nv(const unsigned short* __restrict__ AB,
                                                 const unsigned short* __restrict__ VT,
                                                 const float* __restrict__ dvec,
                                                 unsigned short* YT, float* SpT) {
  __shared__ unsigned short lA[2][4096], lB[2][4096];
  const int mt = blockIdx.x, ct = blockIdx.y, b = blockIdx.z, tid = threadIdx.x;
  const unsigned short* Aop = AB + ((size_t)b << 22) + (size_t)mt * 128 * NN;
  const unsigned short* Bop = VT + (((size_t)(b * NC2 + ct * 128)) << 11);
  f32x4 acc[4][4];
  gemm_core(Aop, NN, Bop, NN, NN / 32, lA[0], lA[1], lB[0], lB[1], tid, acc);
  const int lane = tid & 63, wave = tid >> 6;
  const int wr = wave >> 1, wc = wave & 1, l15 = lane & 15, l4 = (lane >> 4) * 4;
#pragma unroll
  for (int i = 0; i < 4; ++i) {
    const int n0 = mt * 128 + wr * 64 + i * 16 + l4;
#pragma unroll
    for (int j = 0; j < 4; ++j) {
      const int c = ct * 128 + wc * 64 + j * 16 + l15;   // 0..255
      const unsigned short* vt = VT + (((size_t)(b * NC2 + c)) << 11);
      if (ct == 0) {
        u16x4 pk;
#pragma unroll
        for (int r = 0; r < 4; ++r)
          pk[r] = f2b((acc[i][j][r] + b2f(vt[n0 + r])) * dvec[(b << 11) + n0 + r]);
        *(u16x4*)(YT + (((size_t)(b * 384 + c)) << 11) + n0) = pk;
      } else {
        f32x4 pk;
#pragma unroll
        for (int r = 0; r < 4; ++r)
          pk[r] = (acc[i][j][r] + b2f(vt[n0 + r])) * dvec[(b << 11) + n0 + r];
        *(f32x4*)(SpT + (((size_t)(b * 128 + (c - 128))) << 11) + n0) = pk;
      }
    }
  }
}

// row softmax over k=128; writes S fp32 (d_out) + S_T bf16 (YT rows 256..383);
// entropy via  entr = log s - <p, x-m>  (eps shift negligible: ~1e-5)
__global__ __launch_bounds__(128) void k_softmax(const float* __restrict__ SpT,
                                                 float* __restrict__ out,
                                                 unsigned short* __restrict__ YT,
                                                 float* accv) {
  const int t = blockIdx.x, b = blockIdx.y;       // 32 x 8
  const int tid = threadIdx.x;
  const int h = tid >> 6, r = tid & 63;
  const int n = t * 64 + r;
  const float* src = SpT + (((size_t)(b * 128 + h * 64)) << 11) + n;
  float x[64];
  float m = -1e30f;
#pragma unroll
  for (int k = 0; k < 64; ++k) { x[k] = src[(size_t)k << 11]; m = fmaxf(m, x[k]); }
  __shared__ float smx[2][64], sms[2][64], smt[2][64];
  smx[h][r] = m;
  __syncthreads();
  m = fmaxf(smx[0][r], smx[1][r]);
  float s = 0.f, tt = 0.f;
#pragma unroll
  for (int k = 0; k < 64; ++k) {
    const float e = __expf(x[k] - m);
    s += e; tt += (x[k] - m) * e; x[k] = e;
  }
  sms[h][r] = s; smt[h][r] = tt;
  __syncthreads();
  s = sms[0][r] + sms[1][r];
  tt = smt[0][r] + smt[1][r];
  const float inv = 1.f / s;
  float* po = out + OUT_S0 + (((size_t)(b * NN + n)) << 7) + h * 64;
#pragma unroll
  for (int k4 = 0; k4 < 16; ++k4) {
    f32x4 v;
    v[0] = x[k4*4+0]*inv; v[1] = x[k4*4+1]*inv; v[2] = x[k4*4+2]*inv; v[3] = x[k4*4+3]*inv;
    *(f32x4*)(po + k4 * 4) = v;
  }
  unsigned short* pt = YT + (((size_t)(b * 384 + 256 + h * 64)) << 11) + n;
#pragma unroll
  for (int k = 0; k < 64; ++k) pt[(size_t)k << 11] = f2b(x[k] * inv);
  if (h == 0) {
    float entr = __logf(s) - tt * inv;
#pragma unroll
    for (int o2 = 32; o2; o2 >>= 1) entr += __shfl_down(entr, o2);
    if (tid == 0) atomicAdd(&accv[8], entr);
  }
}

// AS_T = (A @ S)^T  -> YT rows 128..255
__global__ __launch_bounds__(256) void k_gemm_as(const unsigned short* __restrict__ AB,
                                                 unsigned short* YT) {
  __shared__ unsigned short lA[2][4096], lB[2][4096];
  const int mt = blockIdx.x, b = blockIdx.z, tid = threadIdx.x;
  const unsigned short* Aop = AB + ((size_t)b << 22) + (size_t)mt * 128 * NN;
  const unsigned short* Bop = YT + (((size_t)(b * 384 + 256)) << 11);
  f32x4 acc[4][4];
  gemm_core(Aop, NN, Bop, NN, NN / 32, lA[0], lA[1], lB[0], lB[1], tid, acc);
  const int lane = tid & 63, wave = tid >> 6;
  const int wr = wave >> 1, wc = wave & 1, l15 = lane & 15, l4 = (lane >> 4) * 4;
#pragma unroll
  for (int i = 0; i < 4; ++i) {
    const int n0 = mt * 128 + wr * 64 + i * 16 + l4;
#pragma unroll
    for (int j = 0; j < 4; ++j) {
      const int c = wc * 64 + j * 16 + l15;
      u16x4 pk;
#pragma unroll
      for (int r = 0; r < 4; ++r) pk[r] = f2b(acc[i][j][r]);
      *(u16x4*)(YT + (((size_t)(b * 384 + 128 + c)) << 11) + n0) = pk;
    }
  }
}

// P = S^T @ [Z | AS | S]  (M=128, N=384, K=2048, split-K=8) -> fp32 partials
__global__ __launch_bounds__(256) void k_gemm_p(const unsigned short* __restrict__ YT,
                                                float* __restrict__ Pp) {
  __shared__ unsigned short lA[2][4096], lB[2][4096];
  const int ct = blockIdx.x, sk = blockIdx.y, b = blockIdx.z, tid = threadIdx.x;
  const unsigned short* Aop = YT + (((size_t)(b * 384 + 256)) << 11) + sk * 256;
  const unsigned short* Bop = YT + (((size_t)(b * 384 + ct * 128)) << 11) + sk * 256;
  f32x4 acc[4][4];
  gemm_core(Aop, NN, Bop, NN, 8, lA[0], lA[1], lB[0], lB[1], tid, acc);
  const int lane = tid & 63, wave = tid >> 6;
  const int wr = wave >> 1, wc = wave & 1, l15 = lane & 15, l4 = (lane >> 4) * 4;
  float* dst = Pp + ((size_t)(sk * NB + b)) * 128 * 384;
#pragma unroll
  for (int i = 0; i < 4; ++i) {
    const int p0 = wr * 64 + i * 16 + l4;
#pragma unroll
    for (int j = 0; j < 4; ++j) {
      const int gc = ct * 128 + wc * 64 + j * 16 + l15;
#pragma unroll
      for (int r = 0; r < 4; ++r) dst[(p0 + r) * 384 + gc] = acc[i][j][r];
    }
  }
}

// sum split-K partials; write X_pooled / A_pooled; per-batch trace + ||S^T S||^2
// nnz_b = sum(rsum[b*2048..]);  LP_b = sqrt(nnz_b - 2 tr + g2);  accv[9] += LP_b/8
__global__ __launch_bounds__(256) void k_finalize(const float* __restrict__ Pp,
                                                  const float* __restrict__ rsum,
                                                  float* accv, float* __restrict__ out) {
  const int b = blockIdx.x, tid = threadIdx.x;
  float tr = 0.f, g2 = 0.f, nz = 0.f;
#pragma unroll
  for (int i = 0; i < 8; ++i) nz += rsum[(b << 11) + i * 256 + tid];
  for (int e = tid; e < 128 * 384; e += 256) {
    const int p = e / 384, c = e % 384;
    float s = 0.f;
#pragma unroll
    for (int sk = 0; sk < 8; ++sk)
      s += Pp[(((size_t)(sk * NB + b)) * 128 + p) * 384 + c];
    if (c < 128) {
      out[OUT_X0 + ((size_t)(b * 128 + p)) * 128 + c] = s;
    } else if (c < 256) {
      out[OUT_A0 + ((size_t)(b * 128 + p)) * 128 + (c - 128)] = s;
      if (c - 128 == p) tr += s;
    } else {
      g2 += s * s;
    }
  }
  __shared__ float rbuf[768];
  rbuf[tid] = tr; rbuf[256 + tid] = g2; rbuf[512 + tid] = nz;
  __syncthreads();
  for (int o = 128; o; o >>= 1) {
    if (tid < o) {
      rbuf[tid] += rbuf[tid + o];
      rbuf[256 + tid] += rbuf[256 + tid + o];
      rbuf[512 + tid] += rbuf[512 + tid + o];
    }
    __syncthreads();
  }
  if (tid == 0) {
    const float lp2 = rbuf[512] - 2.f * rbuf[0] + rbuf[256];
    atomicAdd(&accv[9], 0.125f * sqrtf(fmaxf(lp2, 0.f)));
  }
}

__global__ __launch_bounds__(64) void k_losses(const float* accv, float* out) {
  if (threadIdx.x == 0) {
    out[OUT_LP] = accv[9];
    out[OUT_ENT] = accv[8] * (1.f / (NB * NN));
  }
}

extern "C" void kernel_launch(void* const* d_in, const int* in_sizes, int n_in,
                              void* d_out, int out_size, void* d_ws, size_t ws_size,
                              hipStream_t stream) {
  const float* X     = (const float*)d_in[0];
  const float* A     = (const float*)d_in[1];
  const float* Wemb  = (const float*)d_in[2];
  const float* Wpool = (const float*)d_in[3];
  float* out = (float*)d_out;

  char* ws = (char*)d_ws;
  size_t o = 0;
  unsigned short* AB = (unsigned short*)(ws + o); o += (size_t)NB * NN * NN * 2;   // 64 MiB
  unsigned short* XB = (unsigned short*)(ws + o); o += (size_t)NB * NN * NF * 2;
  unsigned short* WT = (unsigned short*)(ws + o); o += (size_t)NC2 * NF * 2;
  unsigned short* VT = (unsigned short*)(ws + o); o += (size_t)NB * NC2 * NN * 2;
  unsigned short* YT = (unsigned short*)(ws + o); o += (size_t)NB * 384 * NN * 2;  // [Z|AS|S]^T
  float* SpT = (float*)(ws + o); o += (size_t)NB * 128 * NN * 4;
  float* Pp  = (float*)(ws + o); o += (size_t)8 * NB * 128 * 384 * 4;
  float* dvec = (float*)(ws + o); o += (size_t)NB * NN * 4;
  float* rsum = (float*)(ws + o); o += (size_t)NB * NN * 4;
  float* accv = (float*)(ws + o); o += 256;   // [8]=entropy, [9]=LP

  k_zero    <<<1, 64, 0, stream>>>(accv);
  k_prep_a  <<<dim3(NB * NN / 4), 256, 0, stream>>>(A, AB, dvec, rsum);
  k_conv_x  <<<dim3(512), 256, 0, stream>>>(X, XB);
  k_prep_w  <<<dim3(NC2), 128, 0, stream>>>(Wemb, Wpool, WT);
  k_gemm_xw <<<dim3(NB * NN / 128, 2), 256, 0, stream>>>(XB, WT, dvec, VT);
  k_gemm_nv <<<dim3(NN / 128, 2, NB), 256, 0, stream>>>(AB, VT, dvec, YT, SpT);
  k_softmax <<<dim3(NN / 64, NB), 128, 0, stream>>>(SpT, out, YT, accv);
  k_gemm_as <<<dim3(NN / 128, 1, NB), 256, 0, stream>>>(AB, YT);
  k_gemm_p  <<<dim3(3, 8, NB), 256, 0, stream>>>(YT, Pp);
  k_finalize<<<dim3(NB), 256, 0, stream>>>(Pp, rsum, accv, out);
  k_losses  <<<1, 64, 0, stream>>>(accv, out);
}

// Round 3
// 330.605 us; speedup vs baseline: 1.7431x; 1.2694x over previous
//
#include <hip/hip_runtime.h>
#include <math.h>

typedef __bf16 bf16x8 __attribute__((ext_vector_type(8)));
typedef float  f32x4  __attribute__((ext_vector_type(4)));
typedef unsigned short u16x4 __attribute__((ext_vector_type(4)));

#define DEVI __device__ __forceinline__

static constexpr int NB  = 8;
static constexpr int NN  = 2048;
static constexpr int NF  = 128;
static constexpr int NC2 = 256;                    // [W_emb | W_pool] width

static constexpr int OUT_X0  = 0;                  // X_pooled [8,128,128]
static constexpr int OUT_A0  = NB * 128 * 128;     // A_pooled [8,128,128]
static constexpr int OUT_S0  = OUT_A0 + NB * 128 * 128;   // S [8,2048,128]
static constexpr int OUT_LP  = OUT_S0 + NB * NN * 128;    // LP_loss scalar
static constexpr int OUT_ENT = OUT_LP + 1;                // entr_loss scalar

DEVI unsigned short f2b(float f) {                 // fp32 -> bf16 (RNE)
  unsigned int u = __builtin_bit_cast(unsigned int, f);
  u += 0x7fffu + ((u >> 16) & 1u);
  return (unsigned short)(u >> 16);
}
DEVI float b2f(unsigned short h) {
  unsigned int u = ((unsigned int)h) << 16;
  return __builtin_bit_cast(float, u);
}
DEVI void load_lds16(const void* g, void* l) {
  __builtin_amdgcn_global_load_lds(
      (const __attribute__((address_space(1))) void*)g,
      (__attribute__((address_space(3))) void*)l, 16, 0, 0);
}

// ---- 128x128x(K) bf16 MFMA GEMM core (B operand stored transposed [col][k]) ----
// LDS tile: 128 rows x 32 k, slot s = row*4 + c (16B each); slot holds global
// k-chunk (c ^ (row&3)): staging stays 64B-line coalesced, frag reads bank-spread.
DEVI void stage_tile(const unsigned short* src, int ld, unsigned short* dst,
                     int k0, int tid) {
  const int wave = tid >> 6;
#pragma unroll
  for (int is = 0; is < 2; ++is) {
    const int row = is * 64 + (tid >> 2);
    const int c   = tid & 3;
    const unsigned short* g = src + row * ld + k0 + ((c ^ (row & 3)) << 3);
    unsigned short* l = dst + ((is * 256 + wave * 64) << 3);  // wave-uniform base
    load_lds16(g, l);
  }
}

DEVI void gemm_core(const unsigned short* Aop, int lda,
                    const unsigned short* Bop, int ldb, int ksteps,
                    unsigned short* lA0, unsigned short* lA1,
                    unsigned short* lB0, unsigned short* lB1,
                    int tid, f32x4 (&acc)[4][4]) {
  const int lane = tid & 63;
  const int wave = tid >> 6;
  const int wr = wave >> 1, wc = wave & 1;
  const int l15 = lane & 15;
  const int sx = (lane >> 4) ^ (l15 & 3);
#pragma unroll
  for (int i = 0; i < 4; ++i) {
#pragma unroll
    for (int j = 0; j < 4; ++j) acc[i][j] = (f32x4){0.f, 0.f, 0.f, 0.f};
  }
  stage_tile(Aop, lda, lA0, 0, tid);
  stage_tile(Bop, ldb, lB0, 0, tid);
  __syncthreads();
  for (int kt = 0; kt < ksteps; ++kt) {
    unsigned short* curA = (kt & 1) ? lA1 : lA0;
    unsigned short* curB = (kt & 1) ? lB1 : lB0;
    if (kt + 1 < ksteps) {
      unsigned short* nxtA = (kt & 1) ? lA0 : lA1;
      unsigned short* nxtB = (kt & 1) ? lB0 : lB1;
      stage_tile(Aop, lda, nxtA, (kt + 1) * 32, tid);
      stage_tile(Bop, ldb, nxtB, (kt + 1) * 32, tid);
    }
    bf16x8 af[4], bg[4];
#pragma unroll
    for (int i = 0; i < 4; ++i) {
      const int row = wr * 64 + i * 16 + l15;
      af[i] = *(const bf16x8*)(curA + ((row * 4 + sx) << 3));
    }
#pragma unroll
    for (int j = 0; j < 4; ++j) {
      const int col = wc * 64 + j * 16 + l15;
      bg[j] = *(const bf16x8*)(curB + ((col * 4 + sx) << 3));
    }
#pragma unroll
    for (int i = 0; i < 4; ++i) {
#pragma unroll
      for (int j = 0; j < 4; ++j)
        acc[i][j] = __builtin_amdgcn_mfma_f32_16x16x32_bf16(af[i], bg[j],
                                                            acc[i][j], 0, 0, 0);
    }
    __syncthreads();
  }
}

// ---- small kernels ----

// A fp32 -> bf16, rowsum -> d = rsqrt(rowsum+1); rsum[row] = rowsum (NO atomics)
__global__ __launch_bounds__(256) void k_prep_a(const float* __restrict__ A,
                                                unsigned short* __restrict__ AB,
                                                float* __restrict__ dvec,
                                                float* __restrict__ rsum) {
  const int row = blockIdx.x * 4 + (threadIdx.x >> 6);
  const int lane = threadIdx.x & 63;
  const f32x4* src = (const f32x4*)(A + ((size_t)row << 11));
  u16x4* dst = (u16x4*)(AB + ((size_t)row << 11));
  float s = 0.f;
#pragma unroll
  for (int it = 0; it < 8; ++it) {
    f32x4 v = src[it * 64 + lane];
    s += v[0] + v[1] + v[2] + v[3];
    u16x4 o;
    o[0] = f2b(v[0]); o[1] = f2b(v[1]); o[2] = f2b(v[2]); o[3] = f2b(v[3]);
    dst[it * 64 + lane] = o;
  }
#pragma unroll
  for (int o2 = 32; o2; o2 >>= 1) s += __shfl_down(s, o2);
  if (lane == 0) {
    dvec[row] = rsqrtf(s + 1.f);
    rsum[row] = s;
  }
}

__global__ __launch_bounds__(256) void k_conv_x(const float* __restrict__ X,
                                                unsigned short* __restrict__ XB) {
  const int i0 = blockIdx.x * 1024 + threadIdx.x;
  const f32x4* src = (const f32x4*)X;
  u16x4* dst = (u16x4*)XB;
#pragma unroll
  for (int it = 0; it < 4; ++it) {
    const int idx = i0 + it * 256;
    f32x4 v = src[idx];
    u16x4 o;
    o[0] = f2b(v[0]); o[1] = f2b(v[1]); o[2] = f2b(v[2]); o[3] = f2b(v[3]);
    dst[idx] = o;
  }
}

// WT[c][f] = W[f][c] for c<128 from W_emb else W_pool (bf16)
__global__ __launch_bounds__(128) void k_prep_w(const float* __restrict__ Wemb,
                                                const float* __restrict__ Wpool,
                                                unsigned short* __restrict__ WT) {
  const int c = blockIdx.x, f = threadIdx.x;
  const float v = (c < 128) ? Wemb[f * 128 + c] : Wpool[f * 128 + (c - 128)];
  WT[c * 128 + f] = f2b(v);
}

// V_T[b][c][n] = bf16( d[b,n] * (X @ Wcat)[b,n,c] )   (transposed store)
__global__ __launch_bounds__(256) void k_gemm_xw(const unsigned short* __restrict__ XB,
                                                 const unsigned short* __restrict__ WT,
                                                 const float* __restrict__ dvec,
                                                 unsigned short* __restrict__ VT) {
  __shared__ unsigned short lA[2][4096], lB[2][4096];
  const int mt = blockIdx.x, ct = blockIdx.y, tid = threadIdx.x;
  f32x4 acc[4][4];
  gemm_core(XB + mt * 128 * NF, NF, WT + ct * 128 * NF, NF, NF / 32,
            lA[0], lA[1], lB[0], lB[1], tid, acc);
  const int lane = tid & 63, wave = tid >> 6;
  const int wr = wave >> 1, wc = wave & 1, l15 = lane & 15, l4 = (lane >> 4) * 4;
#pragma unroll
  for (int i = 0; i < 4; ++i) {
    const int gr0 = mt * 128 + wr * 64 + i * 16 + l4;   // global row (b*2048+n)
    const int b = gr0 >> 11, n0 = gr0 & 2047;
#pragma unroll
    for (int j = 0; j < 4; ++j) {
      const int gc = ct * 128 + wc * 64 + j * 16 + l15;
      u16x4 pk;
#pragma unroll
      for (int r = 0; r < 4; ++r) pk[r] = f2b(acc[i][j][r] * dvec[gr0 + r]);
      *(u16x4*)(VT + (((size_t)(b * NC2 + gc)) << 11) + n0) = pk;
    }
  }
}

// U = A@V + V, row-scaled by d.  ct==0 -> Z_T bf16 (YT rows 0..127)
//                               ct==1 -> S_pre_T fp32 (softmax input)
__global__ __launch_bounds__(256) void k_gemm_nv(const unsigned short* __restrict__ AB,
                                                 const unsigned short* __restrict__ VT,
                                                 const float* __restrict__ dvec,
                                                 unsigned short* YT, float* SpT) {
  __shared__ unsigned short lA[2][4096], lB[2][4096];
  const int mt = blockIdx.x, ct = blockIdx.y, b = blockIdx.z, tid = threadIdx.x;
  const unsigned short* Aop = AB + ((size_t)b << 22) + (size_t)mt * 128 * NN;
  const unsigned short* Bop = VT + (((size_t)(b * NC2 + ct * 128)) << 11);
  f32x4 acc[4][4];
  gemm_core(Aop, NN, Bop, NN, NN / 32, lA[0], lA[1], lB[0], lB[1], tid, acc);
  const int lane = tid & 63, wave = tid >> 6;
  const int wr = wave >> 1, wc = wave & 1, l15 = lane & 15, l4 = (lane >> 4) * 4;
#pragma unroll
  for (int i = 0; i < 4; ++i) {
    const int n0 = mt * 128 + wr * 64 + i * 16 + l4;
#pragma unroll
    for (int j = 0; j < 4; ++j) {
      const int c = ct * 128 + wc * 64 + j * 16 + l15;   // 0..255
      const unsigned short* vt = VT + (((size_t)(b * NC2 + c)) << 11);
      if (ct == 0) {
        u16x4 pk;
#pragma unroll
        for (int r = 0; r < 4; ++r)
          pk[r] = f2b((acc[i][j][r] + b2f(vt[n0 + r])) * dvec[(b << 11) + n0 + r]);
        *(u16x4*)(YT + (((size_t)(b * 384 + c)) << 11) + n0) = pk;
      } else {
        f32x4 pk;
#pragma unroll
        for (int r = 0; r < 4; ++r)
          pk[r] = (acc[i][j][r] + b2f(vt[n0 + r])) * dvec[(b << 11) + n0 + r];
        *(f32x4*)(SpT + (((size_t)(b * 128 + (c - 128))) << 11) + n0) = pk;
      }
    }
  }
}

// row softmax over k=128; writes S fp32 (d_out) + S_T bf16 (YT rows 256..383);
// entropy partial per block -> entv[b*32+t]  (entr = log s - <p, x-m>)
__global__ __launch_bounds__(128) void k_softmax(const float* __restrict__ SpT,
                                                 float* __restrict__ out,
                                                 unsigned short* __restrict__ YT,
                                                 float* __restrict__ entv) {
  const int t = blockIdx.x, b = blockIdx.y;       // 32 x 8
  const int tid = threadIdx.x;
  const int h = tid >> 6, r = tid & 63;
  const int n = t * 64 + r;
  const float* src = SpT + (((size_t)(b * 128 + h * 64)) << 11) + n;
  float x[64];
  float m = -1e30f;
#pragma unroll
  for (int k = 0; k < 64; ++k) { x[k] = src[(size_t)k << 11]; m = fmaxf(m, x[k]); }
  __shared__ float smx[2][64], sms[2][64], smt[2][64];
  smx[h][r] = m;
  __syncthreads();
  m = fmaxf(smx[0][r], smx[1][r]);
  float s = 0.f, tt = 0.f;
#pragma unroll
  for (int k = 0; k < 64; ++k) {
    const float e = __expf(x[k] - m);
    s += e; tt += (x[k] - m) * e; x[k] = e;
  }
  sms[h][r] = s; smt[h][r] = tt;
  __syncthreads();
  s = sms[0][r] + sms[1][r];
  tt = smt[0][r] + smt[1][r];
  const float inv = 1.f / s;
  float* po = out + OUT_S0 + (((size_t)(b * NN + n)) << 7) + h * 64;
#pragma unroll
  for (int k4 = 0; k4 < 16; ++k4) {
    f32x4 v;
    v[0] = x[k4*4+0]*inv; v[1] = x[k4*4+1]*inv; v[2] = x[k4*4+2]*inv; v[3] = x[k4*4+3]*inv;
    *(f32x4*)(po + k4 * 4) = v;
  }
  unsigned short* pt = YT + (((size_t)(b * 384 + 256 + h * 64)) << 11) + n;
#pragma unroll
  for (int k = 0; k < 64; ++k) pt[(size_t)k << 11] = f2b(x[k] * inv);
  if (h == 0) {
    float entr = __logf(s) - tt * inv;
#pragma unroll
    for (int o2 = 32; o2; o2 >>= 1) entr += __shfl_down(entr, o2);
    if (tid == 0) entv[b * 32 + t] = entr;
  }
}

// AS_T = (A @ S)^T  -> YT rows 128..255
__global__ __launch_bounds__(256) void k_gemm_as(const unsigned short* __restrict__ AB,
                                                 unsigned short* YT) {
  __shared__ unsigned short lA[2][4096], lB[2][4096];
  const int mt = blockIdx.x, b = blockIdx.z, tid = threadIdx.x;
  const unsigned short* Aop = AB + ((size_t)b << 22) + (size_t)mt * 128 * NN;
  const unsigned short* Bop = YT + (((size_t)(b * 384 + 256)) << 11);
  f32x4 acc[4][4];
  gemm_core(Aop, NN, Bop, NN, NN / 32, lA[0], lA[1], lB[0], lB[1], tid, acc);
  const int lane = tid & 63, wave = tid >> 6;
  const int wr = wave >> 1, wc = wave & 1, l15 = lane & 15, l4 = (lane >> 4) * 4;
#pragma unroll
  for (int i = 0; i < 4; ++i) {
    const int n0 = mt * 128 + wr * 64 + i * 16 + l4;
#pragma unroll
    for (int j = 0; j < 4; ++j) {
      const int c = wc * 64 + j * 16 + l15;
      u16x4 pk;
#pragma unroll
      for (int r = 0; r < 4; ++r) pk[r] = f2b(acc[i][j][r]);
      *(u16x4*)(YT + (((size_t)(b * 384 + 128 + c)) << 11) + n0) = pk;
    }
  }
}

// P = S^T @ [Z | AS | S]  (M=128, N=384, K=2048, split-K=8) -> fp32 partials
__global__ __launch_bounds__(256) void k_gemm_p(const unsigned short* __restrict__ YT,
                                                float* __restrict__ Pp) {
  __shared__ unsigned short lA[2][4096], lB[2][4096];
  const int ct = blockIdx.x, sk = blockIdx.y, b = blockIdx.z, tid = threadIdx.x;
  const unsigned short* Aop = YT + (((size_t)(b * 384 + 256)) << 11) + sk * 256;
  const unsigned short* Bop = YT + (((size_t)(b * 384 + ct * 128)) << 11) + sk * 256;
  f32x4 acc[4][4];
  gemm_core(Aop, NN, Bop, NN, 8, lA[0], lA[1], lB[0], lB[1], tid, acc);
  const int lane = tid & 63, wave = tid >> 6;
  const int wr = wave >> 1, wc = wave & 1, l15 = lane & 15, l4 = (lane >> 4) * 4;
  float* dst = Pp + ((size_t)(sk * NB + b)) * 128 * 384;
#pragma unroll
  for (int i = 0; i < 4; ++i) {
    const int p0 = wr * 64 + i * 16 + l4;
#pragma unroll
    for (int j = 0; j < 4; ++j) {
      const int gc = ct * 128 + wc * 64 + j * 16 + l15;
#pragma unroll
      for (int r = 0; r < 4; ++r) dst[(p0 + r) * 384 + gc] = acc[i][j][r];
    }
  }
}

// sum split-K partials (contiguous loads); write X_pooled / A_pooled;
// per-chunk trace & ||S^T S||^2 partials (no atomics)
__global__ __launch_bounds__(256) void k_reduce_p(const float* __restrict__ Pp,
                                                  float* __restrict__ trp,
                                                  float* __restrict__ g2p,
                                                  float* __restrict__ out) {
  const int chunk = blockIdx.x, b = blockIdx.y, tid = threadIdx.x;
  const int e = chunk * 256 + tid;            // 0..49151 within this batch
  const int p = e / 384, c = e - p * 384;
  float s = 0.f;
#pragma unroll
  for (int sk = 0; sk < 8; ++sk)
    s += Pp[((size_t)(sk * NB + b)) * (128 * 384) + e];
  float tr = 0.f, g2 = 0.f;
  if (c < 128) {
    out[OUT_X0 + ((size_t)(b * 128 + p)) * 128 + c] = s;
  } else if (c < 256) {
    out[OUT_A0 + ((size_t)(b * 128 + p)) * 128 + (c - 128)] = s;
    if (c - 128 == p) tr = s;
  } else {
    g2 = s * s;
  }
  __shared__ float rb[512];
  rb[tid] = tr; rb[256 + tid] = g2;
  __syncthreads();
  for (int o = 128; o; o >>= 1) {
    if (tid < o) { rb[tid] += rb[tid + o]; rb[256 + tid] += rb[256 + tid + o]; }
    __syncthreads();
  }
  if (tid == 0) { trp[b * 192 + chunk] = rb[0]; g2p[b * 192 + chunk] = rb[256]; }
}

// per-batch: nnz (from rsum) - 2 tr + g2 -> lpv[b] = ||A - SS^T||_F
__global__ __launch_bounds__(256) void k_lp(const float* __restrict__ rsum,
                                            const float* __restrict__ trp,
                                            const float* __restrict__ g2p,
                                            float* __restrict__ lpv) {
  const int b = blockIdx.x, tid = threadIdx.x;
  float nz = 0.f;
#pragma unroll
  for (int i = 0; i < 8; ++i) nz += rsum[(b << 11) + i * 256 + tid];
  float tr = (tid < 192) ? trp[b * 192 + tid] : 0.f;
  float g2 = (tid < 192) ? g2p[b * 192 + tid] : 0.f;
  __shared__ float rb[768];
  rb[tid] = nz; rb[256 + tid] = tr; rb[512 + tid] = g2;
  __syncthreads();
  for (int o = 128; o; o >>= 1) {
    if (tid < o) {
      rb[tid] += rb[tid + o];
      rb[256 + tid] += rb[256 + tid + o];
      rb[512 + tid] += rb[512 + tid + o];
    }
    __syncthreads();
  }
  if (tid == 0)
    lpv[b] = sqrtf(fmaxf(rb[0] - 2.f * rb[256] + rb[512], 0.f));
}

__global__ __launch_bounds__(256) void k_losses(const float* __restrict__ entv,
                                                const float* __restrict__ lpv,
                                                float* __restrict__ out) {
  const int tid = threadIdx.x;
  __shared__ float rb[256];
  rb[tid] = entv[tid];
  __syncthreads();
  for (int o = 128; o; o >>= 1) {
    if (tid < o) rb[tid] += rb[tid + o];
    __syncthreads();
  }
  if (tid == 0) {
    float lp = 0.f;
#pragma unroll
    for (int b = 0; b < 8; ++b) lp += lpv[b];
    out[OUT_LP] = 0.125f * lp;
    out[OUT_ENT] = rb[0] * (1.f / (NB * NN));
  }
}

extern "C" void kernel_launch(void* const* d_in, const int* in_sizes, int n_in,
                              void* d_out, int out_size, void* d_ws, size_t ws_size,
                              hipStream_t stream) {
  const float* X     = (const float*)d_in[0];
  const float* A     = (const float*)d_in[1];
  const float* Wemb  = (const float*)d_in[2];
  const float* Wpool = (const float*)d_in[3];
  float* out = (float*)d_out;

  char* ws = (char*)d_ws;
  size_t o = 0;
  unsigned short* AB = (unsigned short*)(ws + o); o += (size_t)NB * NN * NN * 2;   // 64 MiB
  unsigned short* XB = (unsigned short*)(ws + o); o += (size_t)NB * NN * NF * 2;
  unsigned short* WT = (unsigned short*)(ws + o); o += (size_t)NC2 * NF * 2;
  unsigned short* VT = (unsigned short*)(ws + o); o += (size_t)NB * NC2 * NN * 2;
  unsigned short* YT = (unsigned short*)(ws + o); o += (size_t)NB * 384 * NN * 2;  // [Z|AS|S]^T
  float* SpT = (float*)(ws + o); o += (size_t)NB * 128 * NN * 4;
  float* Pp  = (float*)(ws + o); o += (size_t)8 * NB * 128 * 384 * 4;
  float* dvec = (float*)(ws + o); o += (size_t)NB * NN * 4;
  float* rsum = (float*)(ws + o); o += (size_t)NB * NN * 4;
  float* trp  = (float*)(ws + o); o += (size_t)NB * 192 * 4;
  float* g2p  = (float*)(ws + o); o += (size_t)NB * 192 * 4;
  float* entv = (float*)(ws + o); o += 256 * 4;
  float* lpv  = (float*)(ws + o); o += NB * 4;

  k_prep_a  <<<dim3(NB * NN / 4), 256, 0, stream>>>(A, AB, dvec, rsum);
  k_conv_x  <<<dim3(512), 256, 0, stream>>>(X, XB);
  k_prep_w  <<<dim3(NC2), 128, 0, stream>>>(Wemb, Wpool, WT);
  k_gemm_xw <<<dim3(NB * NN / 128, 2), 256, 0, stream>>>(XB, WT, dvec, VT);
  k_gemm_nv <<<dim3(NN / 128, 2, NB), 256, 0, stream>>>(AB, VT, dvec, YT, SpT);
  k_softmax <<<dim3(NN / 64, NB), 128, 0, stream>>>(SpT, out, YT, entv);
  k_gemm_as <<<dim3(NN / 128, 1, NB), 256, 0, stream>>>(AB, YT);
  k_gemm_p  <<<dim3(3, 8, NB), 256, 0, stream>>>(YT, Pp);
  k_reduce_p<<<dim3(192, NB), 256, 0, stream>>>(Pp, trp, g2p, out);
  k_lp      <<<dim3(NB), 256, 0, stream>>>(rsum, trp, g2p, lpv);
  k_losses  <<<1, 256, 0, stream>>>(entv, lpv, out);
}

// Round 4
// 323.506 us; speedup vs baseline: 1.7813x; 1.0219x over previous
//
#include <hip/hip_runtime.h>
#include <math.h>

typedef __bf16 bf16x8 __attribute__((ext_vector_type(8)));
typedef float  f32x4  __attribute__((ext_vector_type(4)));
typedef unsigned short u16x4 __attribute__((ext_vector_type(4)));

#define DEVI __device__ __forceinline__

static constexpr int NB  = 8;
static constexpr int NN  = 2048;
static constexpr int NF  = 128;
static constexpr int NC2 = 256;                    // [W_emb | W_pool] width

static constexpr int OUT_X0  = 0;                  // X_pooled [8,128,128]
static constexpr int OUT_A0  = NB * 128 * 128;     // A_pooled [8,128,128]
static constexpr int OUT_S0  = OUT_A0 + NB * 128 * 128;   // S [8,2048,128]
static constexpr int OUT_LP  = OUT_S0 + NB * NN * 128;    // LP_loss scalar
static constexpr int OUT_ENT = OUT_LP + 1;                // entr_loss scalar

DEVI unsigned short f2b(float f) {                 // fp32 -> bf16 (RNE)
  unsigned int u = __builtin_bit_cast(unsigned int, f);
  u += 0x7fffu + ((u >> 16) & 1u);
  return (unsigned short)(u >> 16);
}
DEVI float b2f(unsigned short h) {
  unsigned int u = ((unsigned int)h) << 16;
  return __builtin_bit_cast(float, u);
}
DEVI void load_lds16(const void* g, void* l) {
  __builtin_amdgcn_global_load_lds(
      (const __attribute__((address_space(1))) void*)g,
      (__attribute__((address_space(3))) void*)l, 16, 0, 0);
}

// ---- 128x128x(K) bf16 MFMA GEMM core (B operand stored transposed [col][k]) ----
// LDS tile: 128 rows x 32 k, slot s = row*4 + c (16B each); slot holds global
// k-chunk (c ^ (row&3)): staging stays 64B-line coalesced, frag reads bank-spread.
DEVI void stage_tile(const unsigned short* src, int ld, unsigned short* dst,
                     int k0, int tid) {
  const int wave = tid >> 6;
#pragma unroll
  for (int is = 0; is < 2; ++is) {
    const int row = is * 64 + (tid >> 2);
    const int c   = tid & 3;
    const unsigned short* g = src + row * ld + k0 + ((c ^ (row & 3)) << 3);
    unsigned short* l = dst + ((is * 256 + wave * 64) << 3);  // wave-uniform base
    load_lds16(g, l);
  }
}

DEVI void gemm_core(const unsigned short* Aop, int lda,
                    const unsigned short* Bop, int ldb, int ksteps,
                    unsigned short* lA0, unsigned short* lA1,
                    unsigned short* lB0, unsigned short* lB1,
                    int tid, f32x4 (&acc)[4][4]) {
  const int lane = tid & 63;
  const int wave = tid >> 6;
  const int wr = wave >> 1, wc = wave & 1;
  const int l15 = lane & 15;
  const int sx = (lane >> 4) ^ (l15 & 3);
#pragma unroll
  for (int i = 0; i < 4; ++i) {
#pragma unroll
    for (int j = 0; j < 4; ++j) acc[i][j] = (f32x4){0.f, 0.f, 0.f, 0.f};
  }
  stage_tile(Aop, lda, lA0, 0, tid);
  stage_tile(Bop, ldb, lB0, 0, tid);
  __syncthreads();
  for (int kt = 0; kt < ksteps; ++kt) {
    unsigned short* curA = (kt & 1) ? lA1 : lA0;
    unsigned short* curB = (kt & 1) ? lB1 : lB0;
    if (kt + 1 < ksteps) {
      unsigned short* nxtA = (kt & 1) ? lA0 : lA1;
      unsigned short* nxtB = (kt & 1) ? lB0 : lB1;
      stage_tile(Aop, lda, nxtA, (kt + 1) * 32, tid);
      stage_tile(Bop, ldb, nxtB, (kt + 1) * 32, tid);
    }
    bf16x8 af[4], bg[4];
#pragma unroll
    for (int i = 0; i < 4; ++i) {
      const int row = wr * 64 + i * 16 + l15;
      af[i] = *(const bf16x8*)(curA + ((row * 4 + sx) << 3));
    }
#pragma unroll
    for (int j = 0; j < 4; ++j) {
      const int col = wc * 64 + j * 16 + l15;
      bg[j] = *(const bf16x8*)(curB + ((col * 4 + sx) << 3));
    }
#pragma unroll
    for (int i = 0; i < 4; ++i) {
#pragma unroll
      for (int j = 0; j < 4; ++j)
        acc[i][j] = __builtin_amdgcn_mfma_f32_16x16x32_bf16(af[i], bg[j],
                                                            acc[i][j], 0, 0, 0);
    }
    __syncthreads();
  }
}

// ---- small kernels ----

// A fp32 -> bf16, rowsum -> d = rsqrt(rowsum+1); rsum[row] = rowsum (NO atomics)
__global__ __launch_bounds__(256) void k_prep_a(const float* __restrict__ A,
                                                unsigned short* __restrict__ AB,
                                                float* __restrict__ dvec,
                                                float* __restrict__ rsum) {
  const int row = blockIdx.x * 4 + (threadIdx.x >> 6);
  const int lane = threadIdx.x & 63;
  const f32x4* src = (const f32x4*)(A + ((size_t)row << 11));
  u16x4* dst = (u16x4*)(AB + ((size_t)row << 11));
  float s = 0.f;
#pragma unroll
  for (int it = 0; it < 8; ++it) {
    f32x4 v = src[it * 64 + lane];
    s += v[0] + v[1] + v[2] + v[3];
    u16x4 o;
    o[0] = f2b(v[0]); o[1] = f2b(v[1]); o[2] = f2b(v[2]); o[3] = f2b(v[3]);
    dst[it * 64 + lane] = o;
  }
#pragma unroll
  for (int o2 = 32; o2; o2 >>= 1) s += __shfl_down(s, o2);
  if (lane == 0) {
    dvec[row] = rsqrtf(s + 1.f);
    rsum[row] = s;
  }
}

// blocks 0..511: X fp32->bf16;  blocks 512..527: WT[c][f] = W[f][c] bf16
__global__ __launch_bounds__(256) void k_conv_xw(const float* __restrict__ X,
                                                 const float* __restrict__ Wemb,
                                                 const float* __restrict__ Wpool,
                                                 unsigned short* __restrict__ XB,
                                                 unsigned short* __restrict__ WT) {
  const int blk = blockIdx.x, tid = threadIdx.x;
  if (blk < 512) {
    const int i0 = blk * 1024 + tid;
    const f32x4* src = (const f32x4*)X;
    u16x4* dst = (u16x4*)XB;
#pragma unroll
    for (int it = 0; it < 4; ++it) {
      const int idx = i0 + it * 256;
      f32x4 v = src[idx];
      u16x4 o;
      o[0] = f2b(v[0]); o[1] = f2b(v[1]); o[2] = f2b(v[2]); o[3] = f2b(v[3]);
      dst[idx] = o;
    }
  } else {
    const int e = (blk - 512) * 256 + tid;       // 0..4095
    const int c = e >> 4, f0 = (e & 15) * 8;
    const float* W = (c < 128) ? Wemb : Wpool;
    const int cc = c & 127;
#pragma unroll
    for (int q = 0; q < 8; ++q)
      WT[c * 128 + f0 + q] = f2b(W[(f0 + q) * 128 + cc]);
  }
}

// V_T[b][c][n] = bf16( d[b,n] * (X @ Wcat)[b,n,c] )   (transposed store)
__global__ __launch_bounds__(256) void k_gemm_xw(const unsigned short* __restrict__ XB,
                                                 const unsigned short* __restrict__ WT,
                                                 const float* __restrict__ dvec,
                                                 unsigned short* __restrict__ VT) {
  __shared__ unsigned short lA[2][4096], lB[2][4096];
  const int mt = blockIdx.x, ct = blockIdx.y, tid = threadIdx.x;
  f32x4 acc[4][4];
  gemm_core(XB + mt * 128 * NF, NF, WT + ct * 128 * NF, NF, NF / 32,
            lA[0], lA[1], lB[0], lB[1], tid, acc);
  const int lane = tid & 63, wave = tid >> 6;
  const int wr = wave >> 1, wc = wave & 1, l15 = lane & 15, l4 = (lane >> 4) * 4;
#pragma unroll
  for (int i = 0; i < 4; ++i) {
    const int gr0 = mt * 128 + wr * 64 + i * 16 + l4;   // global row (b*2048+n)
    const int b = gr0 >> 11, n0 = gr0 & 2047;
    const f32x4 dv = *(const f32x4*)(dvec + gr0);
#pragma unroll
    for (int j = 0; j < 4; ++j) {
      const int gc = ct * 128 + wc * 64 + j * 16 + l15;
      u16x4 pk;
#pragma unroll
      for (int r = 0; r < 4; ++r) pk[r] = f2b(acc[i][j][r] * dv[r]);
      *(u16x4*)(VT + (((size_t)(b * NC2 + gc)) << 11) + n0) = pk;
    }
  }
}

// U = (A@V + V) row-scaled by d.
//   ct==0 -> Z_T bf16 (YT rows 0..127)
//   ct==1 -> FUSED row-softmax: S fp32 (d_out) + S_T bf16 (YT rows 256..383)
//            + per-block entropy partial entv[b*16+mt]
__global__ __launch_bounds__(256) void k_gemm_nv(const unsigned short* __restrict__ AB,
                                                 const unsigned short* __restrict__ VT,
                                                 const float* __restrict__ dvec,
                                                 unsigned short* __restrict__ YT,
                                                 float* __restrict__ out,
                                                 float* __restrict__ entv) {
  __shared__ unsigned short lA[2][4096], lB[2][4096];
  const int mt = blockIdx.x, ct = blockIdx.y, b = blockIdx.z, tid = threadIdx.x;
  const unsigned short* Aop = AB + ((size_t)b << 22) + (size_t)mt * 128 * NN;
  const unsigned short* Bop = VT + (((size_t)(b * NC2 + ct * 128)) << 11);
  f32x4 acc[4][4];
  gemm_core(Aop, NN, Bop, NN, NN / 32, lA[0], lA[1], lB[0], lB[1], tid, acc);
  const int lane = tid & 63, wave = tid >> 6;
  const int wr = wave >> 1, wc = wave & 1, l15 = lane & 15, l4g = lane >> 4;
  const int l4 = l4g * 4;
  // add V, scale by d (both ct paths)
  f32x4 dv[4];
#pragma unroll
  for (int i = 0; i < 4; ++i) {
    const int n0 = mt * 128 + wr * 64 + i * 16 + l4;
    dv[i] = *(const f32x4*)(dvec + (b << 11) + n0);
  }
#pragma unroll
  for (int i = 0; i < 4; ++i) {
    const int n0 = mt * 128 + wr * 64 + i * 16 + l4;
#pragma unroll
    for (int j = 0; j < 4; ++j) {
      const int c = ct * 128 + wc * 64 + j * 16 + l15;
      const u16x4 vv = *(const u16x4*)(VT + (((size_t)(b * NC2 + c)) << 11) + n0);
#pragma unroll
      for (int r = 0; r < 4; ++r)
        acc[i][j][r] = (acc[i][j][r] + b2f(vv[r])) * dv[i][r];
    }
  }
  if (ct == 0) {                                   // Z_T path
#pragma unroll
    for (int i = 0; i < 4; ++i) {
      const int n0 = mt * 128 + wr * 64 + i * 16 + l4;
#pragma unroll
      for (int j = 0; j < 4; ++j) {
        const int c = wc * 64 + j * 16 + l15;
        u16x4 pk;
#pragma unroll
        for (int r = 0; r < 4; ++r) pk[r] = f2b(acc[i][j][r]);
        *(u16x4*)(YT + (((size_t)(b * 384 + c)) << 11) + n0) = pk;
      }
    }
    return;                                        // ct is block-uniform
  }
  // ---- fused softmax over k=128 (cols split: 16 l15-lanes x 4 j x 2 wc) ----
  float* mbuf = (float*)lA;                        // [wr*2+wc][64]
  float* sbuf = mbuf + 256;
  float* tbuf = mbuf + 512;
  float* ebuf = mbuf + 768;                        // [8]
  float rm[4][4], rs[4][4], rt[4][4];
#pragma unroll
  for (int i = 0; i < 4; ++i)
#pragma unroll
    for (int r = 0; r < 4; ++r) {
      float m = fmaxf(fmaxf(acc[i][0][r], acc[i][1][r]),
                      fmaxf(acc[i][2][r], acc[i][3][r]));
#pragma unroll
      for (int off = 1; off < 16; off <<= 1) m = fmaxf(m, __shfl_xor(m, off));
      if (l15 == 0) mbuf[(wr * 2 + wc) * 64 + i * 16 + l4 + r] = m;
    }
  __syncthreads();
#pragma unroll
  for (int i = 0; i < 4; ++i)
#pragma unroll
    for (int r = 0; r < 4; ++r) {
      const int row = i * 16 + l4 + r;
      rm[i][r] = fmaxf(mbuf[(wr * 2) * 64 + row], mbuf[(wr * 2 + 1) * 64 + row]);
      rs[i][r] = 0.f; rt[i][r] = 0.f;
    }
#pragma unroll
  for (int i = 0; i < 4; ++i)
#pragma unroll
    for (int j = 0; j < 4; ++j)
#pragma unroll
      for (int r = 0; r < 4; ++r) {
        const float xm = acc[i][j][r] - rm[i][r];
        const float e = __expf(xm);
        acc[i][j][r] = e;
        rs[i][r] += e;
        rt[i][r] += xm * e;
      }
  __syncthreads();                                 // mbuf reuse barrier
#pragma unroll
  for (int i = 0; i < 4; ++i)
#pragma unroll
    for (int r = 0; r < 4; ++r) {
      float s = rs[i][r], t = rt[i][r];
#pragma unroll
      for (int off = 1; off < 16; off <<= 1) {
        s += __shfl_xor(s, off); t += __shfl_xor(t, off);
      }
      if (l15 == 0) {
        sbuf[(wr * 2 + wc) * 64 + i * 16 + l4 + r] = s;
        tbuf[(wr * 2 + wc) * 64 + i * 16 + l4 + r] = t;
      }
    }
  __syncthreads();
  float ent = 0.f;
#pragma unroll
  for (int i = 0; i < 4; ++i)
#pragma unroll
    for (int r = 0; r < 4; ++r) {
      const int row = i * 16 + l4 + r;
      const float s = sbuf[(wr * 2) * 64 + row] + sbuf[(wr * 2 + 1) * 64 + row];
      const float t = tbuf[(wr * 2) * 64 + row] + tbuf[(wr * 2 + 1) * 64 + row];
      const float inv = 1.f / s;
      rs[i][r] = inv;
      ent += __logf(s) - t * inv;
    }
#pragma unroll
  for (int i = 0; i < 4; ++i) {
    const int n0 = mt * 128 + wr * 64 + i * 16 + l4;
#pragma unroll
    for (int j = 0; j < 4; ++j) {
      const int c = wc * 64 + j * 16 + l15;
      u16x4 pk;
#pragma unroll
      for (int r = 0; r < 4; ++r) {
        const float sv = acc[i][j][r] * rs[i][r];
        pk[r] = f2b(sv);
        out[OUT_S0 + (((size_t)((b << 11) + n0 + r)) << 7) + c] = sv;
      }
      *(u16x4*)(YT + (((size_t)(b * 384 + 256 + c)) << 11) + n0) = pk;
    }
  }
  if (wc == 0 && l15 == 0) ebuf[wr * 4 + l4g] = ent;
  __syncthreads();
  if (tid == 0) {
    float e8 = 0.f;
#pragma unroll
    for (int q = 0; q < 8; ++q) e8 += ebuf[q];
    entv[b * 16 + mt] = e8;
  }
}

// AS_T = (A @ S)^T -> YT rows 128..255.  BM=64 tiles: grid (32,1,8)=256 blocks.
__global__ __launch_bounds__(256) void k_gemm_as(const unsigned short* __restrict__ AB,
                                                 unsigned short* __restrict__ YT) {
  __shared__ unsigned short lA[2][2048], lB[2][4096];
  const int mt = blockIdx.x, b = blockIdx.z, tid = threadIdx.x;
  const unsigned short* Aop = AB + ((size_t)b << 22) + (size_t)mt * 64 * NN;
  const unsigned short* Bop = YT + (((size_t)(b * 384 + 256)) << 11);
  const int lane = tid & 63, wave = tid >> 6;
  const int l15 = lane & 15;
  const int sx = (lane >> 4) ^ (l15 & 3);
  f32x4 acc[4][2];
#pragma unroll
  for (int i = 0; i < 4; ++i) {
    acc[i][0] = (f32x4){0.f, 0.f, 0.f, 0.f};
    acc[i][1] = (f32x4){0.f, 0.f, 0.f, 0.f};
  }
  {
    const int row = tid >> 2, c = tid & 3;
    load_lds16(Aop + row * NN + ((c ^ (row & 3)) << 3), lA[0] + (wave << 9));
  }
  stage_tile(Bop, NN, lB[0], 0, tid);
  __syncthreads();
  for (int kt = 0; kt < 64; ++kt) {
    unsigned short* curA = lA[kt & 1];
    unsigned short* curB = lB[kt & 1];
    if (kt + 1 < 64) {
      const int k0 = (kt + 1) * 32;
      const int row = tid >> 2, c = tid & 3;
      load_lds16(Aop + row * NN + k0 + ((c ^ (row & 3)) << 3),
                 lA[(kt + 1) & 1] + (wave << 9));
      stage_tile(Bop, NN, lB[(kt + 1) & 1], k0, tid);
    }
    bf16x8 af[4], bg[2];
#pragma unroll
    for (int i = 0; i < 4; ++i)
      af[i] = *(const bf16x8*)(curA + (((i * 16 + l15) * 4 + sx) << 3));
#pragma unroll
    for (int j = 0; j < 2; ++j) {
      const int col = wave * 32 + j * 16 + l15;
      bg[j] = *(const bf16x8*)(curB + ((col * 4 + sx) << 3));
    }
#pragma unroll
    for (int i = 0; i < 4; ++i) {
#pragma unroll
      for (int j = 0; j < 2; ++j)
        acc[i][j] = __builtin_amdgcn_mfma_f32_16x16x32_bf16(af[i], bg[j],
                                                            acc[i][j], 0, 0, 0);
    }
    __syncthreads();
  }
  const int l4 = (lane >> 4) * 4;
#pragma unroll
  for (int i = 0; i < 4; ++i) {
    const int n0 = mt * 64 + i * 16 + l4;
#pragma unroll
    for (int j = 0; j < 2; ++j) {
      const int c = wave * 32 + j * 16 + l15;
      u16x4 pk;
#pragma unroll
      for (int r = 0; r < 4; ++r) pk[r] = f2b(acc[i][j][r]);
      *(u16x4*)(YT + (((size_t)(b * 384 + 128 + c)) << 11) + n0) = pk;
    }
  }
}

// P = S^T @ [Z | AS | S]  (M=128, N=384, K=2048, split-K=8) -> fp32 partials
__global__ __launch_bounds__(256) void k_gemm_p(const unsigned short* __restrict__ YT,
                                                float* __restrict__ Pp) {
  __shared__ unsigned short lA[2][4096], lB[2][4096];
  const int ct = blockIdx.x, sk = blockIdx.y, b = blockIdx.z, tid = threadIdx.x;
  const unsigned short* Aop = YT + (((size_t)(b * 384 + 256)) << 11) + sk * 256;
  const unsigned short* Bop = YT + (((size_t)(b * 384 + ct * 128)) << 11) + sk * 256;
  f32x4 acc[4][4];
  gemm_core(Aop, NN, Bop, NN, 8, lA[0], lA[1], lB[0], lB[1], tid, acc);
  const int lane = tid & 63, wave = tid >> 6;
  const int wr = wave >> 1, wc = wave & 1, l15 = lane & 15, l4 = (lane >> 4) * 4;
  float* dst = Pp + ((size_t)(sk * NB + b)) * 128 * 384;
#pragma unroll
  for (int i = 0; i < 4; ++i) {
    const int p0 = wr * 64 + i * 16 + l4;
#pragma unroll
    for (int j = 0; j < 4; ++j) {
      const int gc = ct * 128 + wc * 64 + j * 16 + l15;
#pragma unroll
      for (int r = 0; r < 4; ++r) dst[(p0 + r) * 384 + gc] = acc[i][j][r];
    }
  }
}

// sum split-K partials (contiguous loads); write X_pooled / A_pooled;
// per-chunk trace & ||S^T S||^2 partials (no atomics)
__global__ __launch_bounds__(256) void k_reduce_p(const float* __restrict__ Pp,
                                                  float* __restrict__ trp,
                                                  float* __restrict__ g2p,
                                                  float* __restrict__ out) {
  const int chunk = blockIdx.x, b = blockIdx.y, tid = threadIdx.x;
  const int e = chunk * 256 + tid;            // 0..49151 within this batch
  const int p = e / 384, c = e - p * 384;
  float s = 0.f;
#pragma unroll
  for (int sk = 0; sk < 8; ++sk)
    s += Pp[((size_t)(sk * NB + b)) * (128 * 384) + e];
  float tr = 0.f, g2 = 0.f;
  if (c < 128) {
    out[OUT_X0 + ((size_t)(b * 128 + p)) * 128 + c] = s;
  } else if (c < 256) {
    out[OUT_A0 + ((size_t)(b * 128 + p)) * 128 + (c - 128)] = s;
    if (c - 128 == p) tr = s;
  } else {
    g2 = s * s;
  }
  __shared__ float rb[512];
  rb[tid] = tr; rb[256 + tid] = g2;
  __syncthreads();
  for (int o = 128; o; o >>= 1) {
    if (tid < o) { rb[tid] += rb[tid + o]; rb[256 + tid] += rb[256 + tid + o]; }
    __syncthreads();
  }
  if (tid == 0) { trp[b * 192 + chunk] = rb[0]; g2p[b * 192 + chunk] = rb[256]; }
}

// per-batch: nnz (from rsum) - 2 tr + g2 -> lpv[b] = ||A - SS^T||_F
__global__ __launch_bounds__(256) void k_lp(const float* __restrict__ rsum,
                                            const float* __restrict__ trp,
                                            const float* __restrict__ g2p,
                                            float* __restrict__ lpv) {
  const int b = blockIdx.x, tid = threadIdx.x;
  float nz = 0.f;
#pragma unroll
  for (int i = 0; i < 8; ++i) nz += rsum[(b << 11) + i * 256 + tid];
  float tr = (tid < 192) ? trp[b * 192 + tid] : 0.f;
  float g2 = (tid < 192) ? g2p[b * 192 + tid] : 0.f;
  __shared__ float rb[768];
  rb[tid] = nz; rb[256 + tid] = tr; rb[512 + tid] = g2;
  __syncthreads();
  for (int o = 128; o; o >>= 1) {
    if (tid < o) {
      rb[tid] += rb[tid + o];
      rb[256 + tid] += rb[256 + tid + o];
      rb[512 + tid] += rb[512 + tid + o];
    }
    __syncthreads();
  }
  if (tid == 0)
    lpv[b] = sqrtf(fmaxf(rb[0] - 2.f * rb[256] + rb[512], 0.f));
}

__global__ __launch_bounds__(256) void k_losses(const float* __restrict__ entv,
                                                const float* __restrict__ lpv,
                                                float* __restrict__ out) {
  const int tid = threadIdx.x;
  __shared__ float rb[256];
  rb[tid] = (tid < 128) ? entv[tid] : 0.f;
  __syncthreads();
  for (int o = 128; o; o >>= 1) {
    if (tid < o) rb[tid] += rb[tid + o];
    __syncthreads();
  }
  if (tid == 0) {
    float lp = 0.f;
#pragma unroll
    for (int b = 0; b < 8; ++b) lp += lpv[b];
    out[OUT_LP] = 0.125f * lp;
    out[OUT_ENT] = rb[0] * (1.f / (NB * NN));
  }
}

extern "C" void kernel_launch(void* const* d_in, const int* in_sizes, int n_in,
                              void* d_out, int out_size, void* d_ws, size_t ws_size,
                              hipStream_t stream) {
  const float* X     = (const float*)d_in[0];
  const float* A     = (const float*)d_in[1];
  const float* Wemb  = (const float*)d_in[2];
  const float* Wpool = (const float*)d_in[3];
  float* out = (float*)d_out;

  char* ws = (char*)d_ws;
  size_t o = 0;
  unsigned short* AB = (unsigned short*)(ws + o); o += (size_t)NB * NN * NN * 2;   // 64 MiB
  unsigned short* XB = (unsigned short*)(ws + o); o += (size_t)NB * NN * NF * 2;
  unsigned short* WT = (unsigned short*)(ws + o); o += (size_t)NC2 * NF * 2;
  unsigned short* VT = (unsigned short*)(ws + o); o += (size_t)NB * NC2 * NN * 2;
  unsigned short* YT = (unsigned short*)(ws + o); o += (size_t)NB * 384 * NN * 2;  // [Z|AS|S]^T
  float* Pp  = (float*)(ws + o); o += (size_t)8 * NB * 128 * 384 * 4;
  float* dvec = (float*)(ws + o); o += (size_t)NB * NN * 4;
  float* rsum = (float*)(ws + o); o += (size_t)NB * NN * 4;
  float* trp  = (float*)(ws + o); o += (size_t)NB * 192 * 4;
  float* g2p  = (float*)(ws + o); o += (size_t)NB * 192 * 4;
  float* entv = (float*)(ws + o); o += 128 * 4;
  float* lpv  = (float*)(ws + o); o += NB * 4;

  k_prep_a  <<<dim3(NB * NN / 4), 256, 0, stream>>>(A, AB, dvec, rsum);
  k_conv_xw <<<dim3(528), 256, 0, stream>>>(X, Wemb, Wpool, XB, WT);
  k_gemm_xw <<<dim3(NB * NN / 128, 2), 256, 0, stream>>>(XB, WT, dvec, VT);
  k_gemm_nv <<<dim3(NN / 128, 2, NB), 256, 0, stream>>>(AB, VT, dvec, YT, out, entv);
  k_gemm_as <<<dim3(NN / 64, 1, NB), 256, 0, stream>>>(AB, YT);
  k_gemm_p  <<<dim3(3, 8, NB), 256, 0, stream>>>(YT, Pp);
  k_reduce_p<<<dim3(192, NB), 256, 0, stream>>>(Pp, trp, g2p, out);
  k_lp      <<<dim3(NB), 256, 0, stream>>>(rsum, trp, g2p, lpv);
  k_losses  <<<1, 256, 0, stream>>>(entv, lpv, out);
}

// Round 5
// 308.677 us; speedup vs baseline: 1.8669x; 1.0480x over previous
//
#include <hip/hip_runtime.h>
#include <math.h>

typedef __bf16 bf16x8 __attribute__((ext_vector_type(8)));
typedef float  f32x4  __attribute__((ext_vector_type(4)));
typedef unsigned short u16x4 __attribute__((ext_vector_type(4)));

#define DEVI __device__ __forceinline__

static constexpr int NB  = 8;
static constexpr int NN  = 2048;
static constexpr int NF  = 128;
static constexpr int NC2 = 256;                    // [W_emb | W_pool] width
static constexpr int NSK = 16;                     // split-K for gemm_p

static constexpr int OUT_X0  = 0;                  // X_pooled [8,128,128]
static constexpr int OUT_A0  = NB * 128 * 128;     // A_pooled [8,128,128]
static constexpr int OUT_S0  = OUT_A0 + NB * 128 * 128;   // S [8,2048,128]
static constexpr int OUT_LP  = OUT_S0 + NB * NN * 128;    // LP_loss scalar
static constexpr int OUT_ENT = OUT_LP + 1;                // entr_loss scalar

DEVI unsigned short f2b(float f) {                 // fp32 -> bf16 (RNE)
  unsigned int u = __builtin_bit_cast(unsigned int, f);
  u += 0x7fffu + ((u >> 16) & 1u);
  return (unsigned short)(u >> 16);
}
DEVI float b2f(unsigned short h) {
  unsigned int u = ((unsigned int)h) << 16;
  return __builtin_bit_cast(float, u);
}
DEVI void load_lds16(const void* g, void* l) {
  __builtin_amdgcn_global_load_lds(
      (const __attribute__((address_space(1))) void*)g,
      (__attribute__((address_space(3))) void*)l, 16, 0, 0);
}
// LDS tile swizzle: slot row*4+c holds k-chunk (c ^ swz(row)).
// swz=(row>>1)&3 -> b128 reads cover all 8 bank-quads exactly 2-way (free).
DEVI int swz(int row) { return (row >> 1) & 3; }

// stage 128 rows x 32 k (8 KB); 2 loads/thread, 64B-line coalesced
DEVI void stage_b128(const unsigned short* src, int ld, unsigned short* dst,
                     int k0, int tid) {
  const int wave = tid >> 6;
#pragma unroll
  for (int is = 0; is < 2; ++is) {
    const int row = is * 64 + (tid >> 2);
    const int c   = tid & 3;
    load_lds16(src + row * ld + k0 + ((c ^ swz(row)) << 3),
               dst + ((is * 256 + wave * 64) << 3));
  }
}
// stage 64 rows x 32 k (4 KB); 1 load/thread
DEVI void stage_a64(const unsigned short* src, int ld, unsigned short* dst,
                    int k0, int tid) {
  const int wave = tid >> 6;
  const int row = tid >> 2, c = tid & 3;
  load_lds16(src + row * ld + k0 + ((c ^ swz(row)) << 3), dst + (wave << 9));
}

// ---- 64x128xK core: 4 waves, each 64 rows x 32 cols, acc[4][2] ----
DEVI void gemm_core64(const unsigned short* Aop, int lda,
                      const unsigned short* Bop, int ldb, int ksteps,
                      unsigned short* lA0, unsigned short* lA1,
                      unsigned short* lB0, unsigned short* lB1,
                      int tid, f32x4 (&acc)[4][2]) {
  const int lane = tid & 63, wave = tid >> 6;
  const int l15 = lane & 15;
  const int sx = (lane >> 4) ^ ((l15 >> 1) & 3);
#pragma unroll
  for (int i = 0; i < 4; ++i) {
    acc[i][0] = (f32x4){0.f, 0.f, 0.f, 0.f};
    acc[i][1] = (f32x4){0.f, 0.f, 0.f, 0.f};
  }
  stage_a64(Aop, lda, lA0, 0, tid);
  stage_b128(Bop, ldb, lB0, 0, tid);
  __syncthreads();
  for (int kt = 0; kt < ksteps; ++kt) {
    unsigned short* curA = (kt & 1) ? lA1 : lA0;
    unsigned short* curB = (kt & 1) ? lB1 : lB0;
    if (kt + 1 < ksteps) {
      const int k0 = (kt + 1) * 32;
      stage_a64(Aop, lda, (kt & 1) ? lA0 : lA1, k0, tid);
      stage_b128(Bop, ldb, (kt & 1) ? lB0 : lB1, k0, tid);
    }
    bf16x8 af[4], bg[2];
#pragma unroll
    for (int i = 0; i < 4; ++i)
      af[i] = *(const bf16x8*)(curA + (((i * 16 + l15) * 4 + sx) << 3));
#pragma unroll
    for (int j = 0; j < 2; ++j)
      bg[j] = *(const bf16x8*)(curB + (((wave * 32 + j * 16 + l15) * 4 + sx) << 3));
#pragma unroll
    for (int i = 0; i < 4; ++i)
#pragma unroll
      for (int j = 0; j < 2; ++j)
        acc[i][j] = __builtin_amdgcn_mfma_f32_16x16x32_bf16(af[i], bg[j],
                                                            acc[i][j], 0, 0, 0);
    __syncthreads();
  }
}

// ---- 128x128xK core (gemm_p) ----
DEVI void gemm_core128(const unsigned short* Aop, int lda,
                       const unsigned short* Bop, int ldb, int ksteps,
                       unsigned short* lA0, unsigned short* lA1,
                       unsigned short* lB0, unsigned short* lB1,
                       int tid, f32x4 (&acc)[4][4]) {
  const int lane = tid & 63, wave = tid >> 6;
  const int wr = wave >> 1, wc = wave & 1;
  const int l15 = lane & 15;
  const int sx = (lane >> 4) ^ ((l15 >> 1) & 3);
#pragma unroll
  for (int i = 0; i < 4; ++i)
#pragma unroll
    for (int j = 0; j < 4; ++j) acc[i][j] = (f32x4){0.f, 0.f, 0.f, 0.f};
  stage_b128(Aop, lda, lA0, 0, tid);
  stage_b128(Bop, ldb, lB0, 0, tid);
  __syncthreads();
  for (int kt = 0; kt < ksteps; ++kt) {
    unsigned short* curA = (kt & 1) ? lA1 : lA0;
    unsigned short* curB = (kt & 1) ? lB1 : lB0;
    if (kt + 1 < ksteps) {
      const int k0 = (kt + 1) * 32;
      stage_b128(Aop, lda, (kt & 1) ? lA0 : lA1, k0, tid);
      stage_b128(Bop, ldb, (kt & 1) ? lB0 : lB1, k0, tid);
    }
    bf16x8 af[4], bg[4];
#pragma unroll
    for (int i = 0; i < 4; ++i)
      af[i] = *(const bf16x8*)(curA + (((wr * 64 + i * 16 + l15) * 4 + sx) << 3));
#pragma unroll
    for (int j = 0; j < 4; ++j)
      bg[j] = *(const bf16x8*)(curB + (((wc * 64 + j * 16 + l15) * 4 + sx) << 3));
#pragma unroll
    for (int i = 0; i < 4; ++i)
#pragma unroll
      for (int j = 0; j < 4; ++j)
        acc[i][j] = __builtin_amdgcn_mfma_f32_16x16x32_bf16(af[i], bg[j],
                                                            acc[i][j], 0, 0, 0);
    __syncthreads();
  }
}

// ---- prep: blocks 0..4095: A->bf16+rowsum; 4096..4607: X->bf16; rest: WT ----
__global__ __launch_bounds__(256) void k_prep(const float* __restrict__ A,
                                              const float* __restrict__ X,
                                              const float* __restrict__ Wemb,
                                              const float* __restrict__ Wpool,
                                              unsigned short* __restrict__ AB,
                                              unsigned short* __restrict__ XB,
                                              unsigned short* __restrict__ WT,
                                              float* __restrict__ dvec,
                                              float* __restrict__ rsum) {
  const int blk = blockIdx.x, tid = threadIdx.x;
  if (blk < 4096) {
    const int row = blk * 4 + (tid >> 6);
    const int lane = tid & 63;
    const f32x4* src = (const f32x4*)(A + ((size_t)row << 11));
    u16x4* dst = (u16x4*)(AB + ((size_t)row << 11));
    float s = 0.f;
#pragma unroll
    for (int it = 0; it < 8; ++it) {
      f32x4 v = src[it * 64 + lane];
      s += v[0] + v[1] + v[2] + v[3];
      u16x4 o;
      o[0] = f2b(v[0]); o[1] = f2b(v[1]); o[2] = f2b(v[2]); o[3] = f2b(v[3]);
      dst[it * 64 + lane] = o;
    }
#pragma unroll
    for (int o2 = 32; o2; o2 >>= 1) s += __shfl_down(s, o2);
    if (lane == 0) { dvec[row] = rsqrtf(s + 1.f); rsum[row] = s; }
  } else if (blk < 4608) {
    const int i0 = (blk - 4096) * 1024 + tid;
    const f32x4* src = (const f32x4*)X;
    u16x4* dst = (u16x4*)XB;
#pragma unroll
    for (int it = 0; it < 4; ++it) {
      const int idx = i0 + it * 256;
      f32x4 v = src[idx];
      u16x4 o;
      o[0] = f2b(v[0]); o[1] = f2b(v[1]); o[2] = f2b(v[2]); o[3] = f2b(v[3]);
      dst[idx] = o;
    }
  } else {
    const int e = (blk - 4608) * 256 + tid;        // 0..4095
    const int c = e >> 4, f0 = (e & 15) * 8;
    const float* W = (c < 128) ? Wemb : Wpool;
    const int cc = c & 127;
#pragma unroll
    for (int q = 0; q < 8; ++q)
      WT[c * 128 + f0 + q] = f2b(W[(f0 + q) * 128 + cc]);
  }
}

// V_T[b][c][n] = bf16( d[b,n] * (X @ Wcat)[b,n,c] )
__global__ __launch_bounds__(256) void k_gemm_xw(const unsigned short* __restrict__ XB,
                                                 const unsigned short* __restrict__ WT,
                                                 const float* __restrict__ dvec,
                                                 unsigned short* __restrict__ VT) {
  __shared__ unsigned short lA[2][2048], lB[2][4096];
  const int mt = blockIdx.x, ct = blockIdx.y, tid = threadIdx.x;
  f32x4 acc[4][2];
  gemm_core64(XB + mt * 64 * NF, NF, WT + ct * 128 * NF, NF, NF / 32,
              lA[0], lA[1], lB[0], lB[1], tid, acc);
  const int lane = tid & 63, wave = tid >> 6;
  const int l15 = lane & 15, l4 = (lane >> 4) * 4;
#pragma unroll
  for (int i = 0; i < 4; ++i) {
    const int gr0 = mt * 64 + i * 16 + l4;          // global row (b*2048+n)
    const int b = gr0 >> 11, n0 = gr0 & 2047;
    const f32x4 dv = *(const f32x4*)(dvec + gr0);
#pragma unroll
    for (int j = 0; j < 2; ++j) {
      const int gc = ct * 128 + wave * 32 + j * 16 + l15;
      u16x4 pk;
#pragma unroll
      for (int r = 0; r < 4; ++r) pk[r] = f2b(acc[i][j][r] * dv[r]);
      *(u16x4*)(VT + (((size_t)(b * NC2 + gc)) << 11) + n0) = pk;
    }
  }
}

// U = (A@V + V) row-scaled by d.  ct==0 -> Z_T bf16 (YT rows 0..127)
//   ct==1 -> fused row-softmax: S fp32 (d_out) + S_T bf16 (YT rows 256..383)
//            + entropy partial entv[b*32+mt]
__global__ __launch_bounds__(256) void k_gemm_nv(const unsigned short* __restrict__ AB,
                                                 const unsigned short* __restrict__ VT,
                                                 const float* __restrict__ dvec,
                                                 unsigned short* __restrict__ YT,
                                                 float* __restrict__ out,
                                                 float* __restrict__ entv) {
  __shared__ unsigned short lA[2][2048], lB[2][4096];
  const int mt = blockIdx.x, ct = blockIdx.y, b = blockIdx.z, tid = threadIdx.x;
  const unsigned short* Aop = AB + ((size_t)b << 22) + (size_t)mt * 64 * NN;
  const unsigned short* Bop = VT + (((size_t)(b * NC2 + ct * 128)) << 11);
  f32x4 acc[4][2];
  gemm_core64(Aop, NN, Bop, NN, NN / 32, lA[0], lA[1], lB[0], lB[1], tid, acc);
  const int lane = tid & 63, wave = tid >> 6;
  const int l15 = lane & 15, l4g = lane >> 4, l4 = l4g * 4;
  f32x4 dv[4];
#pragma unroll
  for (int i = 0; i < 4; ++i)
    dv[i] = *(const f32x4*)(dvec + (b << 11) + mt * 64 + i * 16 + l4);
#pragma unroll
  for (int i = 0; i < 4; ++i) {
    const int n0 = mt * 64 + i * 16 + l4;
#pragma unroll
    for (int j = 0; j < 2; ++j) {
      const int c = ct * 128 + wave * 32 + j * 16 + l15;
      const u16x4 vv = *(const u16x4*)(VT + (((size_t)(b * NC2 + c)) << 11) + n0);
#pragma unroll
      for (int r = 0; r < 4; ++r)
        acc[i][j][r] = (acc[i][j][r] + b2f(vv[r])) * dv[i][r];
    }
  }
  if (ct == 0) {
#pragma unroll
    for (int i = 0; i < 4; ++i) {
      const int n0 = mt * 64 + i * 16 + l4;
#pragma unroll
      for (int j = 0; j < 2; ++j) {
        const int c = wave * 32 + j * 16 + l15;
        u16x4 pk;
#pragma unroll
        for (int r = 0; r < 4; ++r) pk[r] = f2b(acc[i][j][r]);
        *(u16x4*)(YT + (((size_t)(b * 384 + c)) << 11) + n0) = pk;
      }
    }
    return;                                        // ct is block-uniform
  }
  // ---- fused softmax over k=128 (cols: 4 waves x 2 j x 16 l15) ----
  float* mbuf = (float*)lA;                        // [4][64]
  float* sbuf = mbuf + 256;
  float* tbuf = mbuf + 512;
  float* ebuf = mbuf + 768;                        // [4]
  float rm[4][4], rs[4][4], rt[4][4];
#pragma unroll
  for (int i = 0; i < 4; ++i)
#pragma unroll
    for (int r = 0; r < 4; ++r) {
      float m = fmaxf(acc[i][0][r], acc[i][1][r]);
#pragma unroll
      for (int off = 1; off < 16; off <<= 1) m = fmaxf(m, __shfl_xor(m, off));
      if (l15 == 0) mbuf[wave * 64 + i * 16 + l4 + r] = m;
    }
  __syncthreads();
#pragma unroll
  for (int i = 0; i < 4; ++i)
#pragma unroll
    for (int r = 0; r < 4; ++r) {
      const int row = i * 16 + l4 + r;
      rm[i][r] = fmaxf(fmaxf(mbuf[row], mbuf[64 + row]),
                       fmaxf(mbuf[128 + row], mbuf[192 + row]));
      rs[i][r] = 0.f; rt[i][r] = 0.f;
    }
#pragma unroll
  for (int i = 0; i < 4; ++i)
#pragma unroll
    for (int j = 0; j < 2; ++j)
#pragma unroll
      for (int r = 0; r < 4; ++r) {
        const float xm = acc[i][j][r] - rm[i][r];
        const float e = __expf(xm);
        acc[i][j][r] = e;
        rs[i][r] += e;
        rt[i][r] += xm * e;
      }
#pragma unroll
  for (int i = 0; i < 4; ++i)
#pragma unroll
    for (int r = 0; r < 4; ++r) {
      float s = rs[i][r], t = rt[i][r];
#pragma unroll
      for (int off = 1; off < 16; off <<= 1) {
        s += __shfl_xor(s, off); t += __shfl_xor(t, off);
      }
      if (l15 == 0) {
        sbuf[wave * 64 + i * 16 + l4 + r] = s;
        tbuf[wave * 64 + i * 16 + l4 + r] = t;
      }
    }
  __syncthreads();
  float ent = 0.f;
#pragma unroll
  for (int i = 0; i < 4; ++i)
#pragma unroll
    for (int r = 0; r < 4; ++r) {
      const int row = i * 16 + l4 + r;
      const float s = sbuf[row] + sbuf[64 + row] + sbuf[128 + row] + sbuf[192 + row];
      const float t = tbuf[row] + tbuf[64 + row] + tbuf[128 + row] + tbuf[192 + row];
      const float inv = 1.f / s;
      rs[i][r] = inv;
      ent += __logf(s) - t * inv;
    }
#pragma unroll
  for (int i = 0; i < 4; ++i) {
    const int n0 = mt * 64 + i * 16 + l4;
#pragma unroll
    for (int j = 0; j < 2; ++j) {
      const int c = wave * 32 + j * 16 + l15;
      u16x4 pk;
#pragma unroll
      for (int r = 0; r < 4; ++r) {
        const float sv = acc[i][j][r] * rs[i][r];
        pk[r] = f2b(sv);
        out[OUT_S0 + (((size_t)((b << 11) + n0 + r)) << 7) + c] = sv;
      }
      *(u16x4*)(YT + (((size_t)(b * 384 + 256 + c)) << 11) + n0) = pk;
    }
  }
  if (wave == 0 && l15 == 0) ebuf[l4g] = ent;      // rows counted once by wave 0
  __syncthreads();
  if (tid == 0)
    entv[b * 32 + mt] = ebuf[0] + ebuf[1] + ebuf[2] + ebuf[3];
}

// AS_T = (A @ S)^T -> YT rows 128..255
__global__ __launch_bounds__(256) void k_gemm_as(const unsigned short* __restrict__ AB,
                                                 unsigned short* __restrict__ YT) {
  __shared__ unsigned short lA[2][2048], lB[2][4096];
  const int mt = blockIdx.x, b = blockIdx.z, tid = threadIdx.x;
  const unsigned short* Aop = AB + ((size_t)b << 22) + (size_t)mt * 64 * NN;
  const unsigned short* Bop = YT + (((size_t)(b * 384 + 256)) << 11);
  f32x4 acc[4][2];
  gemm_core64(Aop, NN, Bop, NN, NN / 32, lA[0], lA[1], lB[0], lB[1], tid, acc);
  const int lane = tid & 63, wave = tid >> 6;
  const int l15 = lane & 15, l4 = (lane >> 4) * 4;
#pragma unroll
  for (int i = 0; i < 4; ++i) {
    const int n0 = mt * 64 + i * 16 + l4;
#pragma unroll
    for (int j = 0; j < 2; ++j) {
      const int c = wave * 32 + j * 16 + l15;
      u16x4 pk;
#pragma unroll
      for (int r = 0; r < 4; ++r) pk[r] = f2b(acc[i][j][r]);
      *(u16x4*)(YT + (((size_t)(b * 384 + 128 + c)) << 11) + n0) = pk;
    }
  }
}

// P = S^T @ [Z | AS | S]  (M=128, N=384, K=2048, split-K=16) -> fp32 partials
__global__ __launch_bounds__(256) void k_gemm_p(const unsigned short* __restrict__ YT,
                                                float* __restrict__ Pp) {
  __shared__ unsigned short lA[2][4096], lB[2][4096];
  const int ct = blockIdx.x, sk = blockIdx.y, b = blockIdx.z, tid = threadIdx.x;
  const unsigned short* Aop = YT + (((size_t)(b * 384 + 256)) << 11) + sk * 128;
  const unsigned short* Bop = YT + (((size_t)(b * 384 + ct * 128)) << 11) + sk * 128;
  f32x4 acc[4][4];
  gemm_core128(Aop, NN, Bop, NN, 4, lA[0], lA[1], lB[0], lB[1], tid, acc);
  const int lane = tid & 63, wave = tid >> 6;
  const int wr = wave >> 1, wc = wave & 1, l15 = lane & 15, l4 = (lane >> 4) * 4;
  float* dst = Pp + ((size_t)(sk * NB + b)) * 128 * 384;
#pragma unroll
  for (int i = 0; i < 4; ++i) {
    const int p0 = wr * 64 + i * 16 + l4;
#pragma unroll
    for (int j = 0; j < 4; ++j) {
      const int gc = ct * 128 + wc * 64 + j * 16 + l15;
#pragma unroll
      for (int r = 0; r < 4; ++r) dst[(p0 + r) * 384 + gc] = acc[i][j][r];
    }
  }
}

// sum split-K partials; write X_pooled / A_pooled; trace & ||S^T S||^2 partials
__global__ __launch_bounds__(256) void k_reduce_p(const float* __restrict__ Pp,
                                                  float* __restrict__ trp,
                                                  float* __restrict__ g2p,
                                                  float* __restrict__ out) {
  const int chunk = blockIdx.x, b = blockIdx.y, tid = threadIdx.x;
  const int e = chunk * 256 + tid;
  const int p = e / 384, c = e - p * 384;
  float s = 0.f;
#pragma unroll
  for (int sk = 0; sk < NSK; ++sk)
    s += Pp[((size_t)(sk * NB + b)) * (128 * 384) + e];
  float tr = 0.f, g2 = 0.f;
  if (c < 128) {
    out[OUT_X0 + ((size_t)(b * 128 + p)) * 128 + c] = s;
  } else if (c < 256) {
    out[OUT_A0 + ((size_t)(b * 128 + p)) * 128 + (c - 128)] = s;
    if (c - 128 == p) tr = s;
  } else {
    g2 = s * s;
  }
  __shared__ float rb[512];
  rb[tid] = tr; rb[256 + tid] = g2;
  __syncthreads();
  for (int o = 128; o; o >>= 1) {
    if (tid < o) { rb[tid] += rb[tid + o]; rb[256 + tid] += rb[256 + tid + o]; }
    __syncthreads();
  }
  if (tid == 0) { trp[b * 192 + chunk] = rb[0]; g2p[b * 192 + chunk] = rb[256]; }
}

__global__ __launch_bounds__(256) void k_lp(const float* __restrict__ rsum,
                                            const float* __restrict__ trp,
                                            const float* __restrict__ g2p,
                                            float* __restrict__ lpv) {
  const int b = blockIdx.x, tid = threadIdx.x;
  float nz = 0.f;
#pragma unroll
  for (int i = 0; i < 8; ++i) nz += rsum[(b << 11) + i * 256 + tid];
  float tr = (tid < 192) ? trp[b * 192 + tid] : 0.f;
  float g2 = (tid < 192) ? g2p[b * 192 + tid] : 0.f;
  __shared__ float rb[768];
  rb[tid] = nz; rb[256 + tid] = tr; rb[512 + tid] = g2;
  __syncthreads();
  for (int o = 128; o; o >>= 1) {
    if (tid < o) {
      rb[tid] += rb[tid + o];
      rb[256 + tid] += rb[256 + tid + o];
      rb[512 + tid] += rb[512 + tid + o];
    }
    __syncthreads();
  }
  if (tid == 0)
    lpv[b] = sqrtf(fmaxf(rb[0] - 2.f * rb[256] + rb[512], 0.f));
}

__global__ __launch_bounds__(256) void k_losses(const float* __restrict__ entv,
                                                const float* __restrict__ lpv,
                                                float* __restrict__ out) {
  const int tid = threadIdx.x;
  __shared__ float rb[256];
  rb[tid] = entv[tid];
  __syncthreads();
  for (int o = 128; o; o >>= 1) {
    if (tid < o) rb[tid] += rb[tid + o];
    __syncthreads();
  }
  if (tid == 0) {
    float lp = 0.f;
#pragma unroll
    for (int b = 0; b < 8; ++b) lp += lpv[b];
    out[OUT_LP] = 0.125f * lp;
    out[OUT_ENT] = rb[0] * (1.f / (NB * NN));
  }
}

extern "C" void kernel_launch(void* const* d_in, const int* in_sizes, int n_in,
                              void* d_out, int out_size, void* d_ws, size_t ws_size,
                              hipStream_t stream) {
  const float* X     = (const float*)d_in[0];
  const float* A     = (const float*)d_in[1];
  const float* Wemb  = (const float*)d_in[2];
  const float* Wpool = (const float*)d_in[3];
  float* out = (float*)d_out;

  char* ws = (char*)d_ws;
  size_t o = 0;
  unsigned short* AB = (unsigned short*)(ws + o); o += (size_t)NB * NN * NN * 2;   // 64 MiB
  unsigned short* XB = (unsigned short*)(ws + o); o += (size_t)NB * NN * NF * 2;
  unsigned short* WT = (unsigned short*)(ws + o); o += (size_t)NC2 * NF * 2;
  unsigned short* VT = (unsigned short*)(ws + o); o += (size_t)NB * NC2 * NN * 2;
  unsigned short* YT = (unsigned short*)(ws + o); o += (size_t)NB * 384 * NN * 2;  // [Z|AS|S]^T
  float* Pp  = (float*)(ws + o); o += (size_t)NSK * NB * 128 * 384 * 4;
  float* dvec = (float*)(ws + o); o += (size_t)NB * NN * 4;
  float* rsum = (float*)(ws + o); o += (size_t)NB * NN * 4;
  float* trp  = (float*)(ws + o); o += (size_t)NB * 192 * 4;
  float* g2p  = (float*)(ws + o); o += (size_t)NB * 192 * 4;
  float* entv = (float*)(ws + o); o += 256 * 4;
  float* lpv  = (float*)(ws + o); o += NB * 4;

  k_prep    <<<dim3(4624), 256, 0, stream>>>(A, X, Wemb, Wpool, AB, XB, WT, dvec, rsum);
  k_gemm_xw <<<dim3(NB * NN / 64, 2), 256, 0, stream>>>(XB, WT, dvec, VT);
  k_gemm_nv <<<dim3(NN / 64, 2, NB), 256, 0, stream>>>(AB, VT, dvec, YT, out, entv);
  k_gemm_as <<<dim3(NN / 64, 1, NB), 256, 0, stream>>>(AB, YT);
  k_gemm_p  <<<dim3(3, NSK, NB), 256, 0, stream>>>(YT, Pp);
  k_reduce_p<<<dim3(192, NB), 256, 0, stream>>>(Pp, trp, g2p, out);
  k_lp      <<<dim3(NB), 256, 0, stream>>>(rsum, trp, g2p, lpv);
  k_losses  <<<1, 256, 0, stream>>>(entv, lpv, out);
}